// Round 5
// baseline (557.019 us; speedup 1.0000x reference)
//
#include <hip/hip_runtime.h>
#include <hip/hip_fp16.h>

#define N_NODES 100000
#define N_EDGES 1600000
#define DIM 64
#define NEG_SLOPE 0.01f

// ---- preprocessing bucket geometry ----
#define PNODES 256            // nodes per preproc bucket
#define PNB 391               // ceil(100000/256)
#define BCAP 4608             // slab capacity per bucket (avg fill ~4096, sd ~64)
#define BLOCKS1 512           // scatter blocks (2 per CU)
#define THREADS1 512          // 8 waves
#define EPB (N_EDGES / BLOCKS1)   // 3125 exactly

// ---- source-slice geometry (gather L2 residency) ----
#define NSLICE 4
#define SLICE_N 25000         // 25k nodes * 128B = 3.2 MB < 4 MB per-XCD L2

// ---- fused-kernel tile geometry ----
#define FNODES 64
#define FNB 1563              // ceil(100000/64)

typedef _Float16 half8 __attribute__((ext_vector_type(8)));
typedef float float4v __attribute__((ext_vector_type(4)));

// ---- weight prep: W fp32 [k][f] -> WT16 fp16 transposed [f][k], 4 layers ----
// blocks 4..7 zero gmeta (folds the memset dispatch in here)
__global__ void prep_weights(const float* __restrict__ W0, const float* __restrict__ W1,
                             const float* __restrict__ W2, const float* __restrict__ W3,
                             __half* __restrict__ WT16, int* __restrict__ gmeta) {
    if (blockIdx.x < 4) {
        const float* Ws[4] = {W0, W1, W2, W3};
        const float* W = Ws[blockIdx.x];
        __half* dst = WT16 + (size_t)blockIdx.x * DIM * DIM;
        for (int e = threadIdx.x; e < DIM * DIM; e += 256) {
            int k = e >> 6, f = e & 63;
            dst[f * DIM + k] = __float2half(W[e]);
        }
    } else {
        for (int i = (blockIdx.x - 4) * 256 + threadIdx.x; i < PNB * 32; i += 4 * 256)
            gmeta[i] = 0;
    }
}

// gmeta layout per bucket b (32 ints = 128B):
//   [b*32 + 0]        : slab reservation cursor (bucket total)
//   [b*32 + 16 + s]   : global per-(bucket,slice) edge count

// ---- pass 1: LDS counting-sort scatter (256-node buckets, staged writeout) ----
__global__ __launch_bounds__(THREADS1) void bucket_scatter(const int* __restrict__ src,
                                                           const int* __restrict__ dst,
                                                           int* __restrict__ gmeta,
                                                           int* __restrict__ bdata) {
    __shared__ int cnt4[PNB * NSLICE];
    __shared__ int cntb[PNB];
    __shared__ int lexcl[PNB];
    __shared__ int base[PNB];
    __shared__ int wsum[THREADS1 / 64];
    __shared__ int sorted_e[EPB];
    __shared__ unsigned short sorted_b[EPB];

    const int tid = threadIdx.x;
    for (int i = tid; i < PNB * NSLICE; i += THREADS1) cnt4[i] = 0;
    __syncthreads();

    const int e0 = blockIdx.x * EPB;
    const int e1 = e0 + EPB;

    for (int e = e0 + tid; e < e1; e += THREADS1) {
        int d = dst[e];
        int s = src[e] / SLICE_N;
        atomicAdd(&cnt4[(d >> 8) * NSLICE + s], 1);
    }
    __syncthreads();

    // bucket totals; publish per-(bucket,slice) counts; reserve slab space
    for (int i = tid; i < PNB; i += THREADS1) {
        int c0 = cnt4[i * 4], c1 = cnt4[i * 4 + 1], c2 = cnt4[i * 4 + 2], c3 = cnt4[i * 4 + 3];
        int tot = c0 + c1 + c2 + c3;
        cntb[i] = tot;
        if (c0) atomicAdd(&gmeta[i * 32 + 16], c0);
        if (c1) atomicAdd(&gmeta[i * 32 + 17], c1);
        if (c2) atomicAdd(&gmeta[i * 32 + 18], c2);
        if (c3) atomicAdd(&gmeta[i * 32 + 19], c3);
        base[i] = tot ? atomicAdd(&gmeta[i * 32], tot) : 0;
    }
    __syncthreads();

    // exclusive scan over PNB=391 bucket totals (wave shfl scan + partials)
    int v = (tid < PNB) ? cntb[tid] : 0;
    int incl = v;
#pragma unroll
    for (int sh = 1; sh < 64; sh <<= 1) {
        int up = __shfl_up(incl, sh, 64);
        if ((tid & 63) >= sh) incl += up;
    }
    if ((tid & 63) == 63) wsum[tid >> 6] = incl;
    __syncthreads();
    int wpre = 0;
    for (int w = 0; w < (tid >> 6); ++w) wpre += wsum[w];
    if (tid < PNB) lexcl[tid] = wpre + incl - v;
    // reuse cntb as intra-block cursor
    for (int i = tid; i < PNB; i += THREADS1) cntb[i] = 0;
    __syncthreads();

    for (int e = e0 + tid; e < e1; e += THREADS1) {
        int d = dst[e];
        int b = d >> 8;
        int p = lexcl[b] + atomicAdd(&cntb[b], 1);
        sorted_e[p] = src[e] | ((d & 255) << 17);
        sorted_b[p] = (unsigned short)b;
    }
    __syncthreads();

    // coalesced writeout: long runs of consecutive slots per bucket
    for (int i = tid; i < EPB; i += THREADS1) {
        int b = sorted_b[i];
        bdata[(size_t)b * BCAP + base[b] + (i - lexcl[b])] = sorted_e[i];
    }
}

// ---- pass 2: per-bucket (node,slice) counting sort -> offs2, dinv, csr ----
// csr global layout: 4 slice-major segments; within a segment, node-major.
__global__ __launch_bounds__(256) void bucket_build(const int* __restrict__ bdata,
                                                    const int* __restrict__ gmeta,
                                                    int* __restrict__ offs2,  // [4][N_NODES+1]
                                                    float* __restrict__ dinv,
                                                    int* __restrict__ csr) {
    __shared__ int4 partP[256];
    __shared__ int4 partG[256];
    __shared__ int cnt4l[PNODES * 4];
    __shared__ int exclT[PNODES * 4];
    __shared__ int wsum[4];
    __shared__ int4 bcast[2];

    const int tid = threadIdx.x;
    const int b = blockIdx.x;
    const int sz = gmeta[b * 32];
    const int* bd = bdata + (size_t)b * BCAP;

    // P[s] = slice-s count in buckets < b ; G[s] = grand slice-s total
    int4 P = {0, 0, 0, 0}, G = {0, 0, 0, 0};
    for (int i = tid; i < PNB; i += 256) {
        int4 c = *(const int4*)&gmeta[i * 32 + 16];
        G.x += c.x; G.y += c.y; G.z += c.z; G.w += c.w;
        if (i < b) { P.x += c.x; P.y += c.y; P.z += c.z; P.w += c.w; }
    }
    partP[tid] = P; partG[tid] = G;
    __syncthreads();
    for (int st = 128; st > 0; st >>= 1) {
        if (tid < st) {
            int4 a = partP[tid], c = partP[tid + st];
            a.x += c.x; a.y += c.y; a.z += c.z; a.w += c.w; partP[tid] = a;
            int4 d = partG[tid], e = partG[tid + st];
            d.x += e.x; d.y += e.y; d.z += e.z; d.w += e.w; partG[tid] = d;
        }
        __syncthreads();
    }
    if (tid == 0) { bcast[0] = partP[0]; bcast[1] = partG[0]; }
    __syncthreads();
    const int4 Pv = bcast[0], Gv = bcast[1];
    int cstart[4], segend[4];
    cstart[0] = Pv.x;
    cstart[1] = Gv.x + Pv.y;
    cstart[2] = Gv.x + Gv.y + Pv.z;
    cstart[3] = Gv.x + Gv.y + Gv.z + Pv.w;
    segend[0] = Gv.x;
    segend[1] = Gv.x + Gv.y;
    segend[2] = Gv.x + Gv.y + Gv.z;
    segend[3] = Gv.x + Gv.y + Gv.z + Gv.w;

    for (int i = tid; i < PNODES * 4; i += 256) cnt4l[i] = 0;
    __syncthreads();
    for (int i = tid; i < sz; i += 256) {
        int v = bd[i];
        int dl = v >> 17;
        int sr = v & 0x1FFFF;
        atomicAdd(&cnt4l[dl * 4 + sr / SLICE_N], 1);
    }
    __syncthreads();

    // per-slice exclusive scan over 256 local nodes (thread == local node)
    int myc[4]; int tot = 0;
#pragma unroll
    for (int s = 0; s < 4; ++s) { myc[s] = cnt4l[tid * 4 + s]; tot += myc[s]; }
    for (int s = 0; s < 4; ++s) {
        int val = myc[s], incl = val;
#pragma unroll
        for (int sh = 1; sh < 64; sh <<= 1) {
            int up = __shfl_up(incl, sh, 64);
            if ((tid & 63) >= sh) incl += up;
        }
        if ((tid & 63) == 63) wsum[tid >> 6] = incl;
        __syncthreads();
        int wpre = 0;
        for (int w = 0; w < (tid >> 6); ++w) wpre += wsum[w];
        exclT[tid * 4 + s] = wpre + incl - val;
        __syncthreads();
    }

    const int nb = b * PNODES;
    const int n = nb + tid;
    if (n < N_NODES) {
        dinv[n] = rsqrtf((float)(tot + 1));   // deg incl self-loop
#pragma unroll
        for (int s = 0; s < 4; ++s)
            offs2[s * (N_NODES + 1) + n] = cstart[s] + exclT[tid * 4 + s];
    }
    if (b == PNB - 1 && tid < 4) offs2[tid * (N_NODES + 1) + N_NODES] = segend[tid];

    for (int i = tid; i < PNODES * 4; i += 256) cnt4l[i] = 0;   // reuse as cursor
    __syncthreads();
    for (int i = tid; i < sz; i += 256) {
        int v = bd[i];
        int dl = v >> 17;
        int sr = v & 0x1FFFF;
        int s = sr / SLICE_N;
        int pos = cstart[s] + exclT[dl * 4 + s] + atomicAdd(&cnt4l[dl * 4 + s], 1);
        csr[pos] = sr << 6;   // element offset src*DIM (row-major G)
    }
}

// ---- staging helper: fp32 row -> fp16 LDS ----
__device__ __forceinline__ void stage8f(__half* dst, const float* __restrict__ X, size_t off) {
    float4 f0 = *(const float4*)(X + off);
    float4 f1 = *(const float4*)(X + off + 4);
    __half2 h0 = __floats2half2_rn(f0.x, f0.y);
    __half2 h1 = __floats2half2_rn(f0.z, f0.w);
    __half2 h2 = __floats2half2_rn(f1.x, f1.y);
    __half2 h3 = __floats2half2_rn(f1.z, f1.w);
    uint4 u;
    u.x = *(unsigned int*)&h0; u.y = *(unsigned int*)&h1;
    u.z = *(unsigned int*)&h2; u.w = *(unsigned int*)&h3;
    *(uint4*)dst = u;
}

// ---- MFMA fp16 matmul + dinv (layer 1): G[r][f] = (half) dinv[r] * (x @ W) ----
#define XPAD 72
__global__ __launch_bounds__(256) void mm_kernel(const float* __restrict__ X,
                                                 const __half* __restrict__ WT,  // [f][k]
                                                 const float* __restrict__ dinv,
                                                 __half* __restrict__ G16) {
    __shared__ __align__(16) __half xs[64][XPAD];
    __shared__ __align__(16) __half ws[64][XPAD];
    const int t = threadIdx.x;
    const int rbase = blockIdx.x * 64;

    for (int c = t; c < 512; c += 256) {
        int row = c >> 3, koff = (c & 7) * 8;
        int grow = rbase + row;
        if (grow < N_NODES) {
            stage8f(&xs[row][koff], X, (size_t)grow * DIM + koff);
        } else {
            *(uint4*)&xs[row][koff] = make_uint4(0, 0, 0, 0);
        }
        *(uint4*)&ws[row][koff] = *(const uint4*)(WT + (size_t)row * DIM + koff);
    }
    __syncthreads();

    const int wave = t >> 6;
    const int lane = t & 63;
    const int q = lane >> 4;
    const int c16 = lane & 15;
    const int n0 = wave * 16;

    half8 b0 = *(const half8*)&xs[n0 + c16][q * 8];
    half8 b1 = *(const half8*)&xs[n0 + c16][32 + q * 8];

    const int gnode = rbase + n0 + c16;
    float di = (gnode < N_NODES) ? dinv[gnode] : 0.f;

#pragma unroll
    for (int ft = 0; ft < 4; ++ft) {
        const int f0 = ft * 16;
        half8 a0 = *(const half8*)&ws[f0 + c16][q * 8];
        half8 a1 = *(const half8*)&ws[f0 + c16][32 + q * 8];
        float4v acc = {0.f, 0.f, 0.f, 0.f};
        acc = __builtin_amdgcn_mfma_f32_16x16x32_f16(a0, b0, acc, 0, 0, 0);
        acc = __builtin_amdgcn_mfma_f32_16x16x32_f16(a1, b1, acc, 0, 0, 0);
        if (gnode < N_NODES) {
            __half2 p0 = __floats2half2_rn(di * acc[0], di * acc[1]);
            __half2 p1 = __floats2half2_rn(di * acc[2], di * acc[3]);
            uint2 u;
            u.x = *(unsigned int*)&p0;
            u.y = *(unsigned int*)&p1;
            *(uint2*)(G16 + (size_t)gnode * DIM + f0 + q * 4) = u;
        }
    }
}

// -------- fused: slice-phased agg(layer i) + mm(layer i+1) (or fp32 epilogue) --------
// One block per 64-node bucket. Outer loop over 4 src slices: during phase s the
// whole GPU gathers 128B rows only from a 3.2 MB slice of Gin (per-XCD L2-resident)
// and reads csr's slice-s segment sequentially. Per-slice partials accumulate in an
// LDS fp32 tile. Epilogue: self-loop + dinv + bias + LeakyReLU, then MFMA matmul
// (non-final) or fp32 store (final).
#define FACCP 68
template <bool FINAL>
__global__ __launch_bounds__(256) void fused_agg(const __half* __restrict__ Gin,
                                                 const int* __restrict__ csr,
                                                 const int* __restrict__ offs2,
                                                 const float* __restrict__ dinv,
                                                 const float* __restrict__ bias,
                                                 const __half* __restrict__ WT,
                                                 void* __restrict__ outp) {
    __shared__ __align__(16) __half act[64][XPAD];
    __shared__ __align__(16) __half ws[64][XPAD];
    __shared__ __align__(16) float facc[64][FACCP];
    const int t = threadIdx.x;
    const int nb = blockIdx.x * FNODES;

    if constexpr (!FINAL) {
        for (int c = t; c < 512; c += 256) {
            int row = c >> 3, koff = (c & 7) * 8;
            *(uint4*)&ws[row][koff] = *(const uint4*)(WT + (size_t)row * DIM + koff);
        }
    }
    {   // zero facc used region [64][64]
        int row = t >> 2, f0 = (t & 3) * 16;
        float4 z = {0.f, 0.f, 0.f, 0.f};
        *(float4*)&facc[row][f0] = z;     *(float4*)&facc[row][f0 + 4] = z;
        *(float4*)&facc[row][f0 + 8] = z; *(float4*)&facc[row][f0 + 12] = z;
    }
    __syncthreads();

    const int wave = t >> 6;
    const int lane = t & 63;
    const int grp  = lane >> 5;          // node of the pair
    const int slot = (lane >> 3) & 3;    // 0..3
    const int sub  = lane & 7;           // 16B chunk within row
    const int fc   = sub * 8;

    for (int s = 0; s < NSLICE; ++s) {
        const int* o2 = offs2 + s * (N_NODES + 1);
        for (int i = 0; i < 8; ++i) {
            const int lrow = wave * 16 + i * 2 + grp;
            const int wid = nb + lrow;
            const bool valid = (wid < N_NODES);
            const int beg = valid ? o2[wid] : 0;
            const int end = valid ? o2[wid + 1] : 0;

            __half2 h0 = __float2half2_rn(0.f), h1 = h0, h2 = h0, h3 = h0;
            for (int e = beg + slot; e < end; e += 4) {
                int p0 = csr[e];
                float4 v0 = *(const float4*)(Gin + (size_t)p0 + fc);
                const __half2* hp = (const __half2*)&v0;
                h0 = __hadd2(h0, hp[0]);
                h1 = __hadd2(h1, hp[1]);
                h2 = __hadd2(h2, hp[2]);
                h3 = __hadd2(h3, hp[3]);
            }
            float acc[8];
            {
                float2 f;
                f = __half22float2(h0); acc[0] = f.x; acc[1] = f.y;
                f = __half22float2(h1); acc[2] = f.x; acc[3] = f.y;
                f = __half22float2(h2); acc[4] = f.x; acc[5] = f.y;
                f = __half22float2(h3); acc[6] = f.x; acc[7] = f.y;
            }
#pragma unroll
            for (int k = 0; k < 8; ++k) {
                acc[k] += __shfl_xor(acc[k], 8, 64);
                acc[k] += __shfl_xor(acc[k], 16, 64);
            }
            if (slot == 0 && valid) {   // lanes 0-7 / 32-39: wave-private rows, no race
                float4 a0 = *(float4*)&facc[lrow][fc];
                float4 a1 = *(float4*)&facc[lrow][fc + 4];
                a0.x += acc[0]; a0.y += acc[1]; a0.z += acc[2]; a0.w += acc[3];
                a1.x += acc[4]; a1.y += acc[5]; a1.z += acc[6]; a1.w += acc[7];
                *(float4*)&facc[lrow][fc] = a0;
                *(float4*)&facc[lrow][fc + 4] = a1;
            }
        }
    }
    __syncthreads();

    // epilogue: thread t handles row t>>2, feature quarter (t&3)*16
    {
        const int row = t >> 2, f0 = (t & 3) * 16;
        const int wid = nb + row;
        if (wid < N_NODES) {
            float r[16];
            const float di = dinv[wid];
            const __half* sp = Gin + (size_t)wid * DIM + f0;   // self-loop row
            half8 s0 = *(const half8*)sp;
            half8 s1 = *(const half8*)(sp + 8);
#pragma unroll
            for (int k = 0; k < 8; ++k) {
                r[k]     = facc[row][f0 + k]     + (float)s0[k];
                r[k + 8] = facc[row][f0 + 8 + k] + (float)s1[k];
            }
            const float4 bb0 = *(const float4*)(bias + f0);
            const float4 bb1 = *(const float4*)(bias + f0 + 4);
            const float4 bb2 = *(const float4*)(bias + f0 + 8);
            const float4 bb3 = *(const float4*)(bias + f0 + 12);
            const float bfs[16] = {bb0.x, bb0.y, bb0.z, bb0.w, bb1.x, bb1.y, bb1.z, bb1.w,
                                   bb2.x, bb2.y, bb2.z, bb2.w, bb3.x, bb3.y, bb3.z, bb3.w};
#pragma unroll
            for (int k = 0; k < 16; ++k) {
                float xv = di * r[k] + bfs[k];
                r[k] = (xv >= 0.f) ? xv : NEG_SLOPE * xv;
            }
            if constexpr (FINAL) {
                float* op = (float*)outp + (size_t)wid * DIM + f0;
                *(float4*)op        = make_float4(r[0], r[1], r[2], r[3]);
                *(float4*)(op + 4)  = make_float4(r[4], r[5], r[6], r[7]);
                *(float4*)(op + 8)  = make_float4(r[8], r[9], r[10], r[11]);
                *(float4*)(op + 12) = make_float4(r[12], r[13], r[14], r[15]);
            } else {
                __half2 q[8];
#pragma unroll
                for (int k = 0; k < 8; ++k) q[k] = __floats2half2_rn(r[2 * k], r[2 * k + 1]);
                uint4 u0, u1;
                u0.x = *(unsigned*)&q[0]; u0.y = *(unsigned*)&q[1];
                u0.z = *(unsigned*)&q[2]; u0.w = *(unsigned*)&q[3];
                u1.x = *(unsigned*)&q[4]; u1.y = *(unsigned*)&q[5];
                u1.z = *(unsigned*)&q[6]; u1.w = *(unsigned*)&q[7];
                *(uint4*)&act[row][f0] = u0;
                *(uint4*)&act[row][f0 + 8] = u1;
            }
        } else if constexpr (!FINAL) {
            uint4 z = make_uint4(0, 0, 0, 0);
            *(uint4*)&act[row][f0] = z;
            *(uint4*)&act[row][f0 + 8] = z;
        }
    }

    if constexpr (!FINAL) {
        __syncthreads();
        // mm phase: Gout[n] = dinv[n] * (act[n] @ W)
        const int q_ = lane >> 4;
        const int c16 = lane & 15;
        const int n0 = wave * 16;
        half8 xb0 = *(const half8*)&act[n0 + c16][q_ * 8];
        half8 xb1 = *(const half8*)&act[n0 + c16][32 + q_ * 8];
        const int gnode = nb + n0 + c16;
        const float dio = (gnode < N_NODES) ? dinv[gnode] : 0.f;
        __half* Gout = (__half*)outp;
#pragma unroll
        for (int ft = 0; ft < 4; ++ft) {
            const int f0 = ft * 16;
            half8 a0 = *(const half8*)&ws[f0 + c16][q_ * 8];
            half8 a1 = *(const half8*)&ws[f0 + c16][32 + q_ * 8];
            float4v accv = {0.f, 0.f, 0.f, 0.f};
            accv = __builtin_amdgcn_mfma_f32_16x16x32_f16(a0, xb0, accv, 0, 0, 0);
            accv = __builtin_amdgcn_mfma_f32_16x16x32_f16(a1, xb1, accv, 0, 0, 0);
            if (gnode < N_NODES) {
                __half2 p0 = __floats2half2_rn(dio * accv[0], dio * accv[1]);
                __half2 p1 = __floats2half2_rn(dio * accv[2], dio * accv[3]);
                uint2 u;
                u.x = *(unsigned*)&p0;
                u.y = *(unsigned*)&p1;
                *(uint2*)(Gout + (size_t)gnode * DIM + f0 + q_ * 4) = u;
            }
        }
    }
}

extern "C" void kernel_launch(void* const* d_in, const int* in_sizes, int n_in,
                              void* d_out, int out_size, void* d_ws, size_t ws_size,
                              hipStream_t stream) {
    const float* x = (const float*)d_in[0];
    const int* ei = (const int*)d_in[1];
    const int* src = ei;
    const int* dst = ei + N_EDGES;
    const float* W[4] = {(const float*)d_in[2], (const float*)d_in[4],
                         (const float*)d_in[6], (const float*)d_in[8]};
    const float* b[4] = {(const float*)d_in[3], (const float*)d_in[5],
                         (const float*)d_in[7], (const float*)d_in[9]};
    float* out = (float*)d_out;

    char* ws = (char*)d_ws;
    size_t off = 0;
    auto alloc = [&](size_t bytes) -> void* {
        void* p = ws + off;
        off = (off + bytes + 255) & ~(size_t)255;
        return p;
    };
    __half* GA    = (__half*)alloc((size_t)N_NODES * DIM * sizeof(__half));   // 12.8 MB
    __half* GB    = (__half*)alloc((size_t)N_NODES * DIM * sizeof(__half));   // 12.8 MB
    __half* WT16  = (__half*)alloc((size_t)4 * DIM * DIM * sizeof(__half));   // 32 KB
    int*   csr    = (int*)alloc((size_t)N_EDGES * sizeof(int));               // 6.4 MB
    int*   bdata  = (int*)alloc((size_t)PNB * BCAP * sizeof(int));            // 7.2 MB
    int*   gmeta  = (int*)alloc((size_t)PNB * 32 * sizeof(int));              // 50 KB
    int*   offs2  = (int*)alloc((size_t)NSLICE * (N_NODES + 1) * sizeof(int));// 1.6 MB
    float* dinv   = (float*)alloc((size_t)N_NODES * sizeof(float));

    // prep_weights blocks 0-3 convert W; blocks 4-7 zero gmeta
    prep_weights<<<8, 256, 0, stream>>>(W[0], W[1], W[2], W[3], WT16, gmeta);

    bucket_scatter<<<BLOCKS1, THREADS1, 0, stream>>>(src, dst, gmeta, bdata);
    bucket_build<<<PNB, 256, 0, stream>>>(bdata, gmeta, offs2, dinv, csr);

    const int MM_GRID = (N_NODES + 63) / 64;          // 1563

    // layer 1 transform
    mm_kernel<<<MM_GRID, 256, 0, stream>>>(x, WT16, dinv, GA);
    // slice-phased fused agg(l)+mm(l+1)
    fused_agg<false><<<FNB, 256, 0, stream>>>(GA, csr, offs2, dinv, b[0], WT16 + 1 * DIM * DIM, GB);
    fused_agg<false><<<FNB, 256, 0, stream>>>(GB, csr, offs2, dinv, b[1], WT16 + 2 * DIM * DIM, GA);
    fused_agg<false><<<FNB, 256, 0, stream>>>(GA, csr, offs2, dinv, b[2], WT16 + 3 * DIM * DIM, GB);
    // final aggregate -> fp32 out
    fused_agg<true><<<FNB, 256, 0, stream>>>(GB, csr, offs2, dinv, b[3], WT16, out);
}

// Round 6
// 284.515 us; speedup vs baseline: 1.9578x; 1.9578x over previous
//
#include <hip/hip_runtime.h>
#include <hip/hip_fp16.h>

#define N_NODES 100000
#define N_EDGES 1600000
#define DIM 64
#define NEG_SLOPE 0.01f

// ---- preprocessing bucket geometry (decoupled from fused-kernel tiles) ----
#define PNODES 256            // nodes per preproc bucket
#define PNB 391               // ceil(100000/256)
#define BCAP 4608             // slab capacity per bucket (avg fill ~4092, sd ~64)
#define BLOCKS1 512           // scatter blocks (2 per CU)
#define THREADS1 512          // 8 waves
#define EPB (N_EDGES / BLOCKS1)   // 3125 exactly

// ---- fused-kernel tile geometry ----
#define FNODES 64             // nodes per fused block
#define FNB 1563              // ceil(100000/64)

typedef _Float16 half8 __attribute__((ext_vector_type(8)));
typedef float float4v __attribute__((ext_vector_type(4)));

// ---- weight prep: W fp32 [k][f] -> WT16 fp16 transposed [f][k], 4 layers ----
// blocks 4..7 zero gcur (folds the memset dispatch in here)
__global__ void prep_weights(const float* __restrict__ W0, const float* __restrict__ W1,
                             const float* __restrict__ W2, const float* __restrict__ W3,
                             __half* __restrict__ WT16, int* __restrict__ gcur) {
    if (blockIdx.x < 4) {
        const float* Ws[4] = {W0, W1, W2, W3};
        const float* W = Ws[blockIdx.x];
        __half* dst = WT16 + (size_t)blockIdx.x * DIM * DIM;
        for (int e = threadIdx.x; e < DIM * DIM; e += 256) {
            int k = e >> 6, f = e & 63;
            dst[f * DIM + k] = __float2half(W[e]);
        }
    } else {
        for (int i = (blockIdx.x - 4) * 256 + threadIdx.x; i < PNB * 16; i += 4 * 256)
            gcur[i] = 0;
    }
}

// ---- pass 1: LDS counting-sort scatter (256-node buckets, staged writeout) ----
__global__ __launch_bounds__(THREADS1) void bucket_scatter(const int* __restrict__ src,
                                                           const int* __restrict__ dst,
                                                           int* __restrict__ gcur,   // stride 16 (64B pad)
                                                           int* __restrict__ bdata) {
    __shared__ int cnt[PNB];
    __shared__ int lexcl[PNB];
    __shared__ int base[PNB];
    __shared__ int wsum[THREADS1 / 64];
    __shared__ int sorted_e[EPB];
    __shared__ unsigned short sorted_b[EPB];

    const int tid = threadIdx.x;
    for (int i = tid; i < PNB; i += THREADS1) cnt[i] = 0;
    __syncthreads();

    const int e0 = blockIdx.x * EPB;
    const int e1 = e0 + EPB;

    for (int e = e0 + tid; e < e1; e += THREADS1)
        atomicAdd(&cnt[dst[e] >> 8], 1);
    __syncthreads();

    // exclusive scan over PNB=391 counters: wave-level shfl scan + wave partials
    int v = (tid < PNB) ? cnt[tid] : 0;
    int incl = v;
#pragma unroll
    for (int s = 1; s < 64; s <<= 1) {
        int up = __shfl_up(incl, s, 64);
        if ((tid & 63) >= s) incl += up;
    }
    if ((tid & 63) == 63) wsum[tid >> 6] = incl;
    __syncthreads();
    int wpre = 0;
    for (int w = 0; w < (tid >> 6); ++w) wpre += wsum[w];
    if (tid < PNB) lexcl[tid] = wpre + incl - v;

    // global slab reservation; reuse cnt as intra-block cursor
    for (int i = tid; i < PNB; i += THREADS1) {
        int c = cnt[i];
        base[i] = c ? atomicAdd(&gcur[i * 16], c) : 0;
        cnt[i] = 0;
    }
    __syncthreads();

    for (int e = e0 + tid; e < e1; e += THREADS1) {
        int d = dst[e];
        int b = d >> 8;
        int p = lexcl[b] + atomicAdd(&cnt[b], 1);
        sorted_e[p] = src[e] | ((d & 255) << 17);
        sorted_b[p] = (unsigned short)b;
    }
    __syncthreads();

    // coalesced writeout: runs of avg ~8-16 consecutive slots per bucket
    for (int i = tid; i < EPB; i += THREADS1) {
        int b = sorted_b[i];
        bdata[(size_t)b * BCAP + base[b] + (i - lexcl[b])] = sorted_e[i];
    }
}

// ---- pass 2: per-bucket counting sort -> offsets, dinv, csr (single-writer) ----
__global__ __launch_bounds__(256) void bucket_build(const int* __restrict__ bdata,
                                                    const int* __restrict__ gcur,
                                                    int* __restrict__ offsets,
                                                    float* __restrict__ dinv,
                                                    int* __restrict__ csr) {
    __shared__ int cnt[PNODES];
    __shared__ int excl[PNODES];
    __shared__ int part[256];
    const int tid = threadIdx.x;
    const int b = blockIdx.x;
    const int sz = gcur[b * 16];
    const int* bd = bdata + (size_t)b * BCAP;

    // cbase = sum of bucket sizes for buckets < b (parallel reduce, L2-hot)
    int s = 0;
    for (int i = tid; i < b; i += 256) s += gcur[i * 16];
    part[tid] = s;
    __syncthreads();
    for (int st = 128; st > 0; st >>= 1) {
        if (tid < st) part[tid] += part[tid + st];
        __syncthreads();
    }
    const int cbase = part[0];
    __syncthreads();

    for (int i = tid; i < PNODES; i += 256) cnt[i] = 0;
    __syncthreads();
    for (int i = tid; i < sz; i += 256)
        atomicAdd(&cnt[bd[i] >> 17], 1);
    __syncthreads();
    if (tid == 0) {
        int run = 0;
        for (int j = 0; j < PNODES; ++j) { excl[j] = run; run += cnt[j]; }
    }
    __syncthreads();

    const int nb = b * PNODES;
    for (int i = tid; i < PNODES; i += 256) {
        int n = nb + i;
        if (n < N_NODES) {
            offsets[n] = cbase + excl[i];
            dinv[n] = rsqrtf((float)(cnt[i] + 1));   // deg incl self-loop
        }
    }
    if (b == PNB - 1 && tid == 0) offsets[N_NODES] = N_EDGES;

    for (int i = tid; i < PNODES; i += 256) cnt[i] = 0;   // reuse as cursor
    __syncthreads();
    for (int i = tid; i < sz; i += 256) {
        int v = bd[i];
        int l = v >> 17;
        int pos = cbase + excl[l] + atomicAdd(&cnt[l], 1);
        csr[pos] = (v & 0x1FFFF) << 6;   // element offset src*DIM
    }
}

// ---- staging helpers ----
__device__ __forceinline__ void stage8(__half* dst, const float* __restrict__ X, size_t off) {
    float4 f0 = *(const float4*)(X + off);
    float4 f1 = *(const float4*)(X + off + 4);
    __half2 h0 = __floats2half2_rn(f0.x, f0.y);
    __half2 h1 = __floats2half2_rn(f0.z, f0.w);
    __half2 h2 = __floats2half2_rn(f1.x, f1.y);
    __half2 h3 = __floats2half2_rn(f1.z, f1.w);
    uint4 u;
    u.x = *(unsigned int*)&h0; u.y = *(unsigned int*)&h1;
    u.z = *(unsigned int*)&h2; u.w = *(unsigned int*)&h3;
    *(uint4*)dst = u;
}
__device__ __forceinline__ void stage8(__half* dst, const __half* __restrict__ X, size_t off) {
    *(uint4*)dst = *(const uint4*)(X + off);
}

// ---- MFMA fp16 matmul + dinv: G16[r,f] = (half) dinv[r] * sum_k X[r,k] W[k,f] ----
#define XPAD 72
template <typename TIN>
__global__ __launch_bounds__(256) void mm_kernel(const TIN* __restrict__ X,
                                                 const __half* __restrict__ WT,  // [f][k] fp16
                                                 const float* __restrict__ dinv,
                                                 __half* __restrict__ G16) {
    __shared__ __align__(16) __half xs[64][XPAD];
    __shared__ __align__(16) __half ws[64][XPAD];
    const int t = threadIdx.x;
    const int rbase = blockIdx.x * 64;

    for (int c = t; c < 512; c += 256) {
        int row = c >> 3, koff = (c & 7) * 8;
        int grow = rbase + row;
        if (grow < N_NODES) {
            stage8(&xs[row][koff], X, (size_t)grow * DIM + koff);
        } else {
            *(uint4*)&xs[row][koff] = make_uint4(0, 0, 0, 0);
        }
        stage8(&ws[row][koff], WT, (size_t)row * DIM + koff);
    }
    __syncthreads();

    const int wave = t >> 6;
    const int lane = t & 63;
    const int q = lane >> 4;
    const int c16 = lane & 15;
    const int n0 = wave * 16;

    half8 b0 = *(const half8*)&xs[n0 + c16][q * 8];
    half8 b1 = *(const half8*)&xs[n0 + c16][32 + q * 8];

    const int gnode = rbase + n0 + c16;
    float di = (gnode < N_NODES) ? dinv[gnode] : 0.f;

#pragma unroll
    for (int ft = 0; ft < 4; ++ft) {
        const int f0 = ft * 16;
        half8 a0 = *(const half8*)&ws[f0 + c16][q * 8];
        half8 a1 = *(const half8*)&ws[f0 + c16][32 + q * 8];
        float4v acc = {0.f, 0.f, 0.f, 0.f};
        acc = __builtin_amdgcn_mfma_f32_16x16x32_f16(a0, b0, acc, 0, 0, 0);
        acc = __builtin_amdgcn_mfma_f32_16x16x32_f16(a1, b1, acc, 0, 0, 0);
        if (gnode < N_NODES) {
            __half2 p0 = __floats2half2_rn(di * acc[0], di * acc[1]);
            __half2 p1 = __floats2half2_rn(di * acc[2], di * acc[3]);
            uint2 u;
            u.x = *(unsigned int*)&p0;
            u.y = *(unsigned int*)&p1;
            *(uint2*)(G16 + (size_t)gnode * DIM + f0 + q * 4) = u;
        }
    }
}

// shared 4-deep-MLP gather accumulate: per-slot edge sequence identical to the
// old 2-wide loop (e, e+4, e+8, e+12, ...) so results are bit-identical; the
// 4-wide body just keeps 4 row-loads in flight instead of 2 (MLP for the
// latency-bound L3 gather).
#define PKACC(vraw)                                     \
        {                                               \
            const __half2* hp = (const __half2*)&(vraw);\
            h0 = __hadd2(h0, hp[0]);                    \
            h1 = __hadd2(h1, hp[1]);                    \
            h2 = __hadd2(h2, hp[2]);                    \
            h3 = __hadd2(h3, hp[3]);                    \
        }

// ---------------- fused: agg(layer i) into LDS + mm(layer i+1) ----------------
__global__ __launch_bounds__(256) void fused_agg_mm(const __half* __restrict__ Gin,
                                                    const int* __restrict__ csr,
                                                    const int* __restrict__ offsets,
                                                    const float* __restrict__ dinv,
                                                    const float* __restrict__ bias,
                                                    const __half* __restrict__ WT,  // next layer [f][k]
                                                    __half* __restrict__ Gout) {
    __shared__ __align__(16) __half act[64][XPAD];
    __shared__ __align__(16) __half ws[64][XPAD];
    const int t = threadIdx.x;
    const int blk = blockIdx.x;
    const int nb = blk * FNODES;

    // stage next layer's W tile (read in phase 2, after the barrier)
    for (int c = t; c < 512; c += 256) {
        int row = c >> 3, koff = (c & 7) * 8;
        stage8(&ws[row][koff], WT, (size_t)row * DIM + koff);
    }

    const int wave = t >> 6;
    const int lane = t & 63;
    const int grp  = lane >> 5;          // node of the pair
    const int slot = (lane >> 3) & 3;    // 0..3
    const int sub  = lane & 7;           // 16B chunk within row
    const int fc   = sub * 8;

    // ---- phase 1: aggregate 16 nodes per wave (8 pairs) ----
    for (int i = 0; i < 8; ++i) {
        const int lrow = wave * 16 + i * 2 + grp;   // 0..63 local row
        const int wid = nb + lrow;
        const bool valid = (wid < N_NODES);
        const int beg = valid ? offsets[wid] : 0;
        const int end = valid ? offsets[wid + 1] : 0;

        __half2 h0 = __float2half2_rn(0.f), h1 = h0, h2 = h0, h3 = h0;

        int e = beg + slot;
        for (; e + 12 < end; e += 16) {
            int p0 = csr[e];
            int p1 = csr[e + 4];
            int p2 = csr[e + 8];
            int p3 = csr[e + 12];
            float4 v0 = *(const float4*)(Gin + (size_t)p0 + fc);
            float4 v1 = *(const float4*)(Gin + (size_t)p1 + fc);
            float4 v2 = *(const float4*)(Gin + (size_t)p2 + fc);
            float4 v3 = *(const float4*)(Gin + (size_t)p3 + fc);
            PKACC(v0)
            PKACC(v1)
            PKACC(v2)
            PKACC(v3)
        }
        for (; e + 4 < end; e += 8) {
            int p0 = csr[e];
            int p1 = csr[e + 4];
            float4 v0 = *(const float4*)(Gin + (size_t)p0 + fc);
            float4 v1 = *(const float4*)(Gin + (size_t)p1 + fc);
            PKACC(v0)
            PKACC(v1)
        }
        if (e < end) {
            int p0 = csr[e];
            float4 v0 = *(const float4*)(Gin + (size_t)p0 + fc);
            PKACC(v0)
        }

        float acc[8];
        {
            float2 f;
            f = __half22float2(h0); acc[0] = f.x; acc[1] = f.y;
            f = __half22float2(h1); acc[2] = f.x; acc[3] = f.y;
            f = __half22float2(h2); acc[4] = f.x; acc[5] = f.y;
            f = __half22float2(h3); acc[6] = f.x; acc[7] = f.y;
        }
#pragma unroll
        for (int k = 0; k < 8; ++k) {
            acc[k] += __shfl_xor(acc[k], 8, 64);
            acc[k] += __shfl_xor(acc[k], 16, 64);
        }

        if (slot == 0) {   // lanes 0-7 (node A) and 32-39 (node B): full 64-elem row
            uint4 u = make_uint4(0, 0, 0, 0);
            if (valid) {
                // self-loop row, exactly once, post-reduction
                float4 vs = *(const float4*)(Gin + (size_t)wid * DIM + fc);
                {
                    const __half2* hp = (const __half2*)&vs;
                    float2 f0 = __half22float2(hp[0]);
                    float2 f1 = __half22float2(hp[1]);
                    float2 f2 = __half22float2(hp[2]);
                    float2 f3 = __half22float2(hp[3]);
                    acc[0] += f0.x; acc[1] += f0.y;
                    acc[2] += f1.x; acc[3] += f1.y;
                    acc[4] += f2.x; acc[5] += f2.y;
                    acc[6] += f3.x; acc[7] += f3.y;
                }
                float di = dinv[wid];
                float4 bb0 = *(const float4*)(bias + fc);
                float4 bb1 = *(const float4*)(bias + fc + 4);
                float r[8];
                r[0] = di * acc[0] + bb0.x;
                r[1] = di * acc[1] + bb0.y;
                r[2] = di * acc[2] + bb0.z;
                r[3] = di * acc[3] + bb0.w;
                r[4] = di * acc[4] + bb1.x;
                r[5] = di * acc[5] + bb1.y;
                r[6] = di * acc[6] + bb1.z;
                r[7] = di * acc[7] + bb1.w;
#pragma unroll
                for (int k = 0; k < 8; ++k)
                    r[k] = (r[k] >= 0.f) ? r[k] : NEG_SLOPE * r[k];
                __half2 q0 = __floats2half2_rn(r[0], r[1]);
                __half2 q1 = __floats2half2_rn(r[2], r[3]);
                __half2 q2 = __floats2half2_rn(r[4], r[5]);
                __half2 q3 = __floats2half2_rn(r[6], r[7]);
                u.x = *(unsigned int*)&q0;
                u.y = *(unsigned int*)&q1;
                u.z = *(unsigned int*)&q2;
                u.w = *(unsigned int*)&q3;
            }
            *(uint4*)(&act[lrow][fc]) = u;
        }
    }
    __syncthreads();

    // ---- phase 2: Gout[n] = dinv[n] * (act[n] @ W) ----
    const int q = lane >> 4;
    const int c16 = lane & 15;
    const int n0 = wave * 16;

    half8 xb0 = *(const half8*)&act[n0 + c16][q * 8];
    half8 xb1 = *(const half8*)&act[n0 + c16][32 + q * 8];

    const int gnode = nb + n0 + c16;
    float dio = (gnode < N_NODES) ? dinv[gnode] : 0.f;

#pragma unroll
    for (int ft = 0; ft < 4; ++ft) {
        const int f0 = ft * 16;
        half8 a0 = *(const half8*)&ws[f0 + c16][q * 8];
        half8 a1 = *(const half8*)&ws[f0 + c16][32 + q * 8];
        float4v accv = {0.f, 0.f, 0.f, 0.f};
        accv = __builtin_amdgcn_mfma_f32_16x16x32_f16(a0, xb0, accv, 0, 0, 0);
        accv = __builtin_amdgcn_mfma_f32_16x16x32_f16(a1, xb1, accv, 0, 0, 0);
        if (gnode < N_NODES) {
            __half2 p0 = __floats2half2_rn(dio * accv[0], dio * accv[1]);
            __half2 p1 = __floats2half2_rn(dio * accv[2], dio * accv[3]);
            uint2 u;
            u.x = *(unsigned int*)&p0;
            u.y = *(unsigned int*)&p1;
            *(uint2*)(Gout + (size_t)gnode * DIM + f0 + q * 4) = u;
        }
    }
}

// ---------------- final aggregate: persistent waves, 2 nodes per wave ----------------
#define AGG_BLOCKS 2048
#define AGG_WAVES (AGG_BLOCKS * 4)
#define NPAIRS (N_NODES / 2)
template <bool FINAL>
__global__ __launch_bounds__(256) void agg_kernel(const __half* __restrict__ G16,
                                                  const int* __restrict__ csr,
                                                  const int* __restrict__ offsets,
                                                  const float* __restrict__ dinv,
                                                  const float* __restrict__ bias,
                                                  void* __restrict__ outp) {
    const int gw = (blockIdx.x * 256 + threadIdx.x) >> 6;   // global wave id
    const int lane = threadIdx.x & 63;
    const int grp  = lane >> 5;          // node of the pair
    const int slot = (lane >> 3) & 3;    // 0..3
    const int sub  = lane & 7;           // 16B chunk within row
    const int fc   = sub * 8;

    for (int p = gw; p < NPAIRS; p += AGG_WAVES) {
        const int wid = p * 2 + grp;
        const int beg = offsets[wid], end = offsets[wid + 1];

        __half2 h0 = __float2half2_rn(0.f), h1 = h0, h2 = h0, h3 = h0;

        int e = beg + slot;
        for (; e + 12 < end; e += 16) {
            int p0 = csr[e];
            int p1 = csr[e + 4];
            int p2 = csr[e + 8];
            int p3 = csr[e + 12];
            float4 v0 = *(const float4*)(G16 + (size_t)p0 + fc);
            float4 v1 = *(const float4*)(G16 + (size_t)p1 + fc);
            float4 v2 = *(const float4*)(G16 + (size_t)p2 + fc);
            float4 v3 = *(const float4*)(G16 + (size_t)p3 + fc);
            PKACC(v0)
            PKACC(v1)
            PKACC(v2)
            PKACC(v3)
        }
        for (; e + 4 < end; e += 8) {
            int p0 = csr[e];
            int p1 = csr[e + 4];
            float4 v0 = *(const float4*)(G16 + (size_t)p0 + fc);
            float4 v1 = *(const float4*)(G16 + (size_t)p1 + fc);
            PKACC(v0)
            PKACC(v1)
        }
        if (e < end) {
            int p0 = csr[e];
            float4 v0 = *(const float4*)(G16 + (size_t)p0 + fc);
            PKACC(v0)
        }

        float acc[8];
        {
            float2 f;
            f = __half22float2(h0); acc[0] = f.x; acc[1] = f.y;
            f = __half22float2(h1); acc[2] = f.x; acc[3] = f.y;
            f = __half22float2(h2); acc[4] = f.x; acc[5] = f.y;
            f = __half22float2(h3); acc[6] = f.x; acc[7] = f.y;
        }
#pragma unroll
        for (int k = 0; k < 8; ++k) {
            acc[k] += __shfl_xor(acc[k], 8, 64);
            acc[k] += __shfl_xor(acc[k], 16, 64);
        }

        if (slot == 0) {   // lanes 0-7 (node A) and 32-39 (node B)
            float4 vs = *(const float4*)(G16 + (size_t)wid * DIM + fc);
            {
                const __half2* hp = (const __half2*)&vs;
                float2 f0 = __half22float2(hp[0]);
                float2 f1 = __half22float2(hp[1]);
                float2 f2 = __half22float2(hp[2]);
                float2 f3 = __half22float2(hp[3]);
                acc[0] += f0.x; acc[1] += f0.y;
                acc[2] += f1.x; acc[3] += f1.y;
                acc[4] += f2.x; acc[5] += f2.y;
                acc[6] += f3.x; acc[7] += f3.y;
            }

            float di = dinv[wid];
            float4 b0 = *(const float4*)(bias + fc);
            float4 b1 = *(const float4*)(bias + fc + 4);
            float r[8];
            r[0] = di * acc[0] + b0.x;
            r[1] = di * acc[1] + b0.y;
            r[2] = di * acc[2] + b0.z;
            r[3] = di * acc[3] + b0.w;
            r[4] = di * acc[4] + b1.x;
            r[5] = di * acc[5] + b1.y;
            r[6] = di * acc[6] + b1.z;
            r[7] = di * acc[7] + b1.w;
#pragma unroll
            for (int k = 0; k < 8; ++k)
                r[k] = (r[k] >= 0.f) ? r[k] : NEG_SLOPE * r[k];

            if (FINAL) {
                float* out = (float*)outp;
                *(float4*)(out + (size_t)wid * DIM + fc)     = make_float4(r[0], r[1], r[2], r[3]);
                *(float4*)(out + (size_t)wid * DIM + fc + 4) = make_float4(r[4], r[5], r[6], r[7]);
            } else {
                __half* act = (__half*)outp;
                __half2 q0 = __floats2half2_rn(r[0], r[1]);
                __half2 q1 = __floats2half2_rn(r[2], r[3]);
                __half2 q2 = __floats2half2_rn(r[4], r[5]);
                __half2 q3 = __floats2half2_rn(r[6], r[7]);
                uint4 u;
                u.x = *(unsigned int*)&q0;
                u.y = *(unsigned int*)&q1;
                u.z = *(unsigned int*)&q2;
                u.w = *(unsigned int*)&q3;
                *(uint4*)(act + (size_t)wid * DIM + fc) = u;
            }
        }
    }
}
#undef PKACC

extern "C" void kernel_launch(void* const* d_in, const int* in_sizes, int n_in,
                              void* d_out, int out_size, void* d_ws, size_t ws_size,
                              hipStream_t stream) {
    const float* x = (const float*)d_in[0];
    const int* ei = (const int*)d_in[1];
    const int* src = ei;
    const int* dst = ei + N_EDGES;
    const float* W[4] = {(const float*)d_in[2], (const float*)d_in[4],
                         (const float*)d_in[6], (const float*)d_in[8]};
    const float* b[4] = {(const float*)d_in[3], (const float*)d_in[5],
                         (const float*)d_in[7], (const float*)d_in[9]};
    float* out = (float*)d_out;

    char* ws = (char*)d_ws;
    size_t off = 0;
    auto alloc = [&](size_t bytes) -> void* {
        void* p = ws + off;
        off = (off + bytes + 255) & ~(size_t)255;
        return p;
    };
    __half* GA    = (__half*)alloc((size_t)N_NODES * DIM * sizeof(__half));   // 12.8 MB
    __half* GB    = (__half*)alloc((size_t)N_NODES * DIM * sizeof(__half));   // 12.8 MB
    __half* WT16  = (__half*)alloc((size_t)4 * DIM * DIM * sizeof(__half));   // 32 KB
    int*   csr    = (int*)alloc((size_t)N_EDGES * sizeof(int));               // 6.4 MB
    int*   bdata  = (int*)alloc((size_t)PNB * BCAP * sizeof(int));            // 7.2 MB
    int*   gcur   = (int*)alloc((size_t)PNB * 16 * sizeof(int));              // 25 KB
    int*   offsets= (int*)alloc((size_t)(N_NODES + 1) * sizeof(int));
    float* dinv   = (float*)alloc((size_t)N_NODES * sizeof(float));

    // prep_weights blocks 0-3 convert W; blocks 4-7 zero gcur (memset folded in)
    prep_weights<<<8, 256, 0, stream>>>(W[0], W[1], W[2], W[3], WT16, gcur);

    bucket_scatter<<<BLOCKS1, THREADS1, 0, stream>>>(src, dst, gcur, bdata);
    bucket_build<<<PNB, 256, 0, stream>>>(bdata, gcur, offsets, dinv, csr);

    const int MM_GRID = (N_NODES + 63) / 64;          // 1563

    // layer 1 transform
    mm_kernel<float><<<MM_GRID, 256, 0, stream>>>(x, WT16, dinv, GA);
    // fused agg(l1)+mm(l2), agg(l2)+mm(l3), agg(l3)+mm(l4)
    fused_agg_mm<<<FNB, 256, 0, stream>>>(GA, csr, offsets, dinv, b[0], WT16 + 1 * DIM * DIM, GB);
    fused_agg_mm<<<FNB, 256, 0, stream>>>(GB, csr, offsets, dinv, b[1], WT16 + 2 * DIM * DIM, GA);
    fused_agg_mm<<<FNB, 256, 0, stream>>>(GA, csr, offsets, dinv, b[2], WT16 + 3 * DIM * DIM, GB);
    // final aggregate -> fp32 out
    agg_kernel<true><<<AGG_BLOCKS, 256, 0, stream>>>(GB, csr, offsets, dinv, b[3], out);
}

// Round 7
// 282.822 us; speedup vs baseline: 1.9695x; 1.0060x over previous
//
#include <hip/hip_runtime.h>
#include <hip/hip_fp16.h>

#define N_NODES 100000
#define N_EDGES 1600000
#define DIM 64
#define NEG_SLOPE 0.01f

// ---- preprocessing bucket geometry (decoupled from fused-kernel tiles) ----
#define PNODES 256            // nodes per preproc bucket
#define PNB 391               // ceil(100000/256)
#define BCAP 4608             // slab capacity per bucket (avg fill ~4092, sd ~64)
#define BLOCKS1 512           // scatter blocks (2 per CU)
#define THREADS1 1024         // 16 waves -> 32 waves/CU during scatter
#define EPB (N_EDGES / BLOCKS1)   // 3125 exactly

// ---- fused-kernel tile geometry ----
#define FNODES 64             // nodes per fused block
#define FNB 1563              // ceil(100000/64)

typedef _Float16 half8 __attribute__((ext_vector_type(8)));
typedef float float4v __attribute__((ext_vector_type(4)));

// ---- weight prep: W fp32 [k][f] -> WT16 fp16 transposed [f][k], 4 layers ----
// blocks 4..7 zero gcur (folds the memset dispatch in here)
__global__ void prep_weights(const float* __restrict__ W0, const float* __restrict__ W1,
                             const float* __restrict__ W2, const float* __restrict__ W3,
                             __half* __restrict__ WT16, int* __restrict__ gcur) {
    if (blockIdx.x < 4) {
        const float* Ws[4] = {W0, W1, W2, W3};
        const float* W = Ws[blockIdx.x];
        __half* dst = WT16 + (size_t)blockIdx.x * DIM * DIM;
        for (int e = threadIdx.x; e < DIM * DIM; e += 256) {
            int k = e >> 6, f = e & 63;
            dst[f * DIM + k] = __float2half(W[e]);
        }
    } else {
        for (int i = (blockIdx.x - 4) * 256 + threadIdx.x; i < PNB * 16; i += 4 * 256)
            gcur[i] = 0;
    }
}

// ---- pass 1: LDS counting-sort scatter (256-node buckets, staged writeout) ----
__global__ __launch_bounds__(THREADS1) void bucket_scatter(const int* __restrict__ src,
                                                           const int* __restrict__ dst,
                                                           int* __restrict__ gcur,   // stride 16 (64B pad)
                                                           int* __restrict__ bdata) {
    __shared__ int cnt[PNB];
    __shared__ int lexcl[PNB];
    __shared__ int base[PNB];
    __shared__ int wsum[THREADS1 / 64];
    __shared__ int sorted_e[EPB];
    __shared__ unsigned short sorted_b[EPB];

    const int tid = threadIdx.x;
    for (int i = tid; i < PNB; i += THREADS1) cnt[i] = 0;
    __syncthreads();

    const int e0 = blockIdx.x * EPB;
    const int e1 = e0 + EPB;

    for (int e = e0 + tid; e < e1; e += THREADS1)
        atomicAdd(&cnt[dst[e] >> 8], 1);
    __syncthreads();

    // exclusive scan over PNB=391 counters: wave-level shfl scan + wave partials
    int v = (tid < PNB) ? cnt[tid] : 0;
    int incl = v;
#pragma unroll
    for (int s = 1; s < 64; s <<= 1) {
        int up = __shfl_up(incl, s, 64);
        if ((tid & 63) >= s) incl += up;
    }
    if ((tid & 63) == 63) wsum[tid >> 6] = incl;
    __syncthreads();
    int wpre = 0;
    for (int w = 0; w < (tid >> 6); ++w) wpre += wsum[w];
    if (tid < PNB) lexcl[tid] = wpre + incl - v;

    // global slab reservation; reuse cnt as intra-block cursor
    for (int i = tid; i < PNB; i += THREADS1) {
        int c = cnt[i];
        base[i] = c ? atomicAdd(&gcur[i * 16], c) : 0;
        cnt[i] = 0;
    }
    __syncthreads();

    for (int e = e0 + tid; e < e1; e += THREADS1) {
        int d = dst[e];
        int b = d >> 8;
        int p = lexcl[b] + atomicAdd(&cnt[b], 1);
        sorted_e[p] = src[e] | ((d & 255) << 17);
        sorted_b[p] = (unsigned short)b;
    }
    __syncthreads();

    // coalesced writeout: runs of avg ~8 consecutive slots per bucket
    for (int i = tid; i < EPB; i += THREADS1) {
        int b = sorted_b[i];
        bdata[(size_t)b * BCAP + base[b] + (i - lexcl[b])] = sorted_e[i];
    }
}

// ---- pass 2: per-bucket counting sort -> offsets, dinv, csr (parallel scan) ----
__global__ __launch_bounds__(256) void bucket_build(const int* __restrict__ bdata,
                                                    const int* __restrict__ gcur,
                                                    int* __restrict__ offsets,
                                                    float* __restrict__ dinv,
                                                    int* __restrict__ csr) {
    __shared__ int cnt[PNODES];
    __shared__ int excl[PNODES];
    __shared__ int part[256];
    __shared__ int wsum[4];
    const int tid = threadIdx.x;
    const int b = blockIdx.x;
    const int sz = gcur[b * 16];
    const int* bd = bdata + (size_t)b * BCAP;

    // cbase = sum of bucket sizes for buckets < b (parallel reduce, L2-hot)
    int s = 0;
    for (int i = tid; i < b; i += 256) s += gcur[i * 16];
    part[tid] = s;
    __syncthreads();
    for (int st = 128; st > 0; st >>= 1) {
        if (tid < st) part[tid] += part[tid + st];
        __syncthreads();
    }
    const int cbase = part[0];
    __syncthreads();

    cnt[tid] = 0;
    __syncthreads();
    for (int i = tid; i < sz; i += 256)
        atomicAdd(&cnt[bd[i] >> 17], 1);
    __syncthreads();

    // parallel exclusive scan over 256 counters (tid == local node)
    {
        int v = cnt[tid];
        int incl = v;
#pragma unroll
        for (int sh = 1; sh < 64; sh <<= 1) {
            int up = __shfl_up(incl, sh, 64);
            if ((tid & 63) >= sh) incl += up;
        }
        if ((tid & 63) == 63) wsum[tid >> 6] = incl;
        __syncthreads();
        int wpre = 0;
        for (int w = 0; w < (tid >> 6); ++w) wpre += wsum[w];
        excl[tid] = wpre + incl - v;
    }
    __syncthreads();

    const int nb = b * PNODES;
    {
        int n = nb + tid;
        if (n < N_NODES) {
            offsets[n] = cbase + excl[tid];
            dinv[n] = rsqrtf((float)(cnt[tid] + 1));   // deg incl self-loop
        }
    }
    if (b == PNB - 1 && tid == 0) offsets[N_NODES] = N_EDGES;

    cnt[tid] = 0;   // reuse as cursor
    __syncthreads();
    for (int i = tid; i < sz; i += 256) {
        int v = bd[i];
        int l = v >> 17;
        int pos = cbase + excl[l] + atomicAdd(&cnt[l], 1);
        csr[pos] = (v & 0x1FFFF) << 6;   // element offset src*DIM
    }
}

// ---- staging helpers ----
__device__ __forceinline__ void stage8(__half* dst, const float* __restrict__ X, size_t off) {
    float4 f0 = *(const float4*)(X + off);
    float4 f1 = *(const float4*)(X + off + 4);
    __half2 h0 = __floats2half2_rn(f0.x, f0.y);
    __half2 h1 = __floats2half2_rn(f0.z, f0.w);
    __half2 h2 = __floats2half2_rn(f1.x, f1.y);
    __half2 h3 = __floats2half2_rn(f1.z, f1.w);
    uint4 u;
    u.x = *(unsigned int*)&h0; u.y = *(unsigned int*)&h1;
    u.z = *(unsigned int*)&h2; u.w = *(unsigned int*)&h3;
    *(uint4*)dst = u;
}
__device__ __forceinline__ void stage8(__half* dst, const __half* __restrict__ X, size_t off) {
    *(uint4*)dst = *(const uint4*)(X + off);
}

// ---- MFMA fp16 matmul + dinv: G16[r,f] = (half) dinv[r] * sum_k X[r,k] W[k,f] ----
#define XPAD 72
template <typename TIN>
__global__ __launch_bounds__(256) void mm_kernel(const TIN* __restrict__ X,
                                                 const __half* __restrict__ WT,  // [f][k] fp16
                                                 const float* __restrict__ dinv,
                                                 __half* __restrict__ G16) {
    __shared__ __align__(16) __half xs[64][XPAD];
    __shared__ __align__(16) __half ws[64][XPAD];
    const int t = threadIdx.x;
    const int rbase = blockIdx.x * 64;

    for (int c = t; c < 512; c += 256) {
        int row = c >> 3, koff = (c & 7) * 8;
        int grow = rbase + row;
        if (grow < N_NODES) {
            stage8(&xs[row][koff], X, (size_t)grow * DIM + koff);
        } else {
            *(uint4*)&xs[row][koff] = make_uint4(0, 0, 0, 0);
        }
        stage8(&ws[row][koff], WT, (size_t)row * DIM + koff);
    }
    __syncthreads();

    const int wave = t >> 6;
    const int lane = t & 63;
    const int q = lane >> 4;
    const int c16 = lane & 15;
    const int n0 = wave * 16;

    half8 b0 = *(const half8*)&xs[n0 + c16][q * 8];
    half8 b1 = *(const half8*)&xs[n0 + c16][32 + q * 8];

    const int gnode = rbase + n0 + c16;
    float di = (gnode < N_NODES) ? dinv[gnode] : 0.f;

#pragma unroll
    for (int ft = 0; ft < 4; ++ft) {
        const int f0 = ft * 16;
        half8 a0 = *(const half8*)&ws[f0 + c16][q * 8];
        half8 a1 = *(const half8*)&ws[f0 + c16][32 + q * 8];
        float4v acc = {0.f, 0.f, 0.f, 0.f};
        acc = __builtin_amdgcn_mfma_f32_16x16x32_f16(a0, b0, acc, 0, 0, 0);
        acc = __builtin_amdgcn_mfma_f32_16x16x32_f16(a1, b1, acc, 0, 0, 0);
        if (gnode < N_NODES) {
            __half2 p0 = __floats2half2_rn(di * acc[0], di * acc[1]);
            __half2 p1 = __floats2half2_rn(di * acc[2], di * acc[3]);
            uint2 u;
            u.x = *(unsigned int*)&p0;
            u.y = *(unsigned int*)&p1;
            *(uint2*)(G16 + (size_t)gnode * DIM + f0 + q * 4) = u;
        }
    }
}

// shared 4-deep-MLP gather accumulate: per-slot edge sequence identical to the
// old 2-wide loop (e, e+4, e+8, e+12, ...) so results are bit-identical.
#define PKACC(vraw)                                     \
        {                                               \
            const __half2* hp = (const __half2*)&(vraw);\
            h0 = __hadd2(h0, hp[0]);                    \
            h1 = __hadd2(h1, hp[1]);                    \
            h2 = __hadd2(h2, hp[2]);                    \
            h3 = __hadd2(h3, hp[3]);                    \
        }

// ---------------- fused: agg(layer i) into LDS + mm(layer i+1) ----------------
__global__ __launch_bounds__(256) void fused_agg_mm(const __half* __restrict__ Gin,
                                                    const int* __restrict__ csr,
                                                    const int* __restrict__ offsets,
                                                    const float* __restrict__ dinv,
                                                    const float* __restrict__ bias,
                                                    const __half* __restrict__ WT,  // next layer [f][k]
                                                    __half* __restrict__ Gout) {
    __shared__ __align__(16) __half act[64][XPAD];
    __shared__ __align__(16) __half ws[64][XPAD];
    const int t = threadIdx.x;
    const int blk = blockIdx.x;
    const int nb = blk * FNODES;

    // stage next layer's W tile (read in phase 2, after the barrier)
    for (int c = t; c < 512; c += 256) {
        int row = c >> 3, koff = (c & 7) * 8;
        stage8(&ws[row][koff], WT, (size_t)row * DIM + koff);
    }

    const int wave = t >> 6;
    const int lane = t & 63;
    const int grp  = lane >> 5;          // node of the pair
    const int slot = (lane >> 3) & 3;    // 0..3
    const int sub  = lane & 7;           // 16B chunk within row
    const int fc   = sub * 8;

    // ---- phase 1: aggregate 16 nodes per wave (8 pairs) ----
    for (int i = 0; i < 8; ++i) {
        const int lrow = wave * 16 + i * 2 + grp;   // 0..63 local row
        const int wid = nb + lrow;
        const bool valid = (wid < N_NODES);
        const int beg = valid ? offsets[wid] : 0;
        const int end = valid ? offsets[wid + 1] : 0;

        __half2 h0 = __float2half2_rn(0.f), h1 = h0, h2 = h0, h3 = h0;

        int e = beg + slot;
        for (; e + 12 < end; e += 16) {
            int p0 = csr[e];
            int p1 = csr[e + 4];
            int p2 = csr[e + 8];
            int p3 = csr[e + 12];
            float4 v0 = *(const float4*)(Gin + (size_t)p0 + fc);
            float4 v1 = *(const float4*)(Gin + (size_t)p1 + fc);
            float4 v2 = *(const float4*)(Gin + (size_t)p2 + fc);
            float4 v3 = *(const float4*)(Gin + (size_t)p3 + fc);
            PKACC(v0)
            PKACC(v1)
            PKACC(v2)
            PKACC(v3)
        }
        for (; e + 4 < end; e += 8) {
            int p0 = csr[e];
            int p1 = csr[e + 4];
            float4 v0 = *(const float4*)(Gin + (size_t)p0 + fc);
            float4 v1 = *(const float4*)(Gin + (size_t)p1 + fc);
            PKACC(v0)
            PKACC(v1)
        }
        if (e < end) {
            int p0 = csr[e];
            float4 v0 = *(const float4*)(Gin + (size_t)p0 + fc);
            PKACC(v0)
        }

        float acc[8];
        {
            float2 f;
            f = __half22float2(h0); acc[0] = f.x; acc[1] = f.y;
            f = __half22float2(h1); acc[2] = f.x; acc[3] = f.y;
            f = __half22float2(h2); acc[4] = f.x; acc[5] = f.y;
            f = __half22float2(h3); acc[6] = f.x; acc[7] = f.y;
        }
#pragma unroll
        for (int k = 0; k < 8; ++k) {
            acc[k] += __shfl_xor(acc[k], 8, 64);
            acc[k] += __shfl_xor(acc[k], 16, 64);
        }

        if (slot == 0) {   // lanes 0-7 (node A) and 32-39 (node B): full 64-elem row
            uint4 u = make_uint4(0, 0, 0, 0);
            if (valid) {
                // self-loop row, exactly once, post-reduction
                float4 vs = *(const float4*)(Gin + (size_t)wid * DIM + fc);
                {
                    const __half2* hp = (const __half2*)&vs;
                    float2 f0 = __half22float2(hp[0]);
                    float2 f1 = __half22float2(hp[1]);
                    float2 f2 = __half22float2(hp[2]);
                    float2 f3 = __half22float2(hp[3]);
                    acc[0] += f0.x; acc[1] += f0.y;
                    acc[2] += f1.x; acc[3] += f1.y;
                    acc[4] += f2.x; acc[5] += f2.y;
                    acc[6] += f3.x; acc[7] += f3.y;
                }
                float di = dinv[wid];
                float4 bb0 = *(const float4*)(bias + fc);
                float4 bb1 = *(const float4*)(bias + fc + 4);
                float r[8];
                r[0] = di * acc[0] + bb0.x;
                r[1] = di * acc[1] + bb0.y;
                r[2] = di * acc[2] + bb0.z;
                r[3] = di * acc[3] + bb0.w;
                r[4] = di * acc[4] + bb1.x;
                r[5] = di * acc[5] + bb1.y;
                r[6] = di * acc[6] + bb1.z;
                r[7] = di * acc[7] + bb1.w;
#pragma unroll
                for (int k = 0; k < 8; ++k)
                    r[k] = (r[k] >= 0.f) ? r[k] : NEG_SLOPE * r[k];
                __half2 q0 = __floats2half2_rn(r[0], r[1]);
                __half2 q1 = __floats2half2_rn(r[2], r[3]);
                __half2 q2 = __floats2half2_rn(r[4], r[5]);
                __half2 q3 = __floats2half2_rn(r[6], r[7]);
                u.x = *(unsigned int*)&q0;
                u.y = *(unsigned int*)&q1;
                u.z = *(unsigned int*)&q2;
                u.w = *(unsigned int*)&q3;
            }
            *(uint4*)(&act[lrow][fc]) = u;
        }
    }
    __syncthreads();

    // ---- phase 2: Gout[n] = dinv[n] * (act[n] @ W) ----
    const int q = lane >> 4;
    const int c16 = lane & 15;
    const int n0 = wave * 16;

    half8 xb0 = *(const half8*)&act[n0 + c16][q * 8];
    half8 xb1 = *(const half8*)&act[n0 + c16][32 + q * 8];

    const int gnode = nb + n0 + c16;
    float dio = (gnode < N_NODES) ? dinv[gnode] : 0.f;

#pragma unroll
    for (int ft = 0; ft < 4; ++ft) {
        const int f0 = ft * 16;
        half8 a0 = *(const half8*)&ws[f0 + c16][q * 8];
        half8 a1 = *(const half8*)&ws[f0 + c16][32 + q * 8];
        float4v accv = {0.f, 0.f, 0.f, 0.f};
        accv = __builtin_amdgcn_mfma_f32_16x16x32_f16(a0, xb0, accv, 0, 0, 0);
        accv = __builtin_amdgcn_mfma_f32_16x16x32_f16(a1, xb1, accv, 0, 0, 0);
        if (gnode < N_NODES) {
            __half2 p0 = __floats2half2_rn(dio * accv[0], dio * accv[1]);
            __half2 p1 = __floats2half2_rn(dio * accv[2], dio * accv[3]);
            uint2 u;
            u.x = *(unsigned int*)&p0;
            u.y = *(unsigned int*)&p1;
            *(uint2*)(Gout + (size_t)gnode * DIM + f0 + q * 4) = u;
        }
    }
}

// ---------------- final aggregate: persistent waves, 2 nodes per wave ----------------
#define AGG_BLOCKS 2048
#define AGG_WAVES (AGG_BLOCKS * 4)
#define NPAIRS (N_NODES / 2)
template <bool FINAL>
__global__ __launch_bounds__(256) void agg_kernel(const __half* __restrict__ G16,
                                                  const int* __restrict__ csr,
                                                  const int* __restrict__ offsets,
                                                  const float* __restrict__ dinv,
                                                  const float* __restrict__ bias,
                                                  void* __restrict__ outp) {
    const int gw = (blockIdx.x * 256 + threadIdx.x) >> 6;   // global wave id
    const int lane = threadIdx.x & 63;
    const int grp  = lane >> 5;          // node of the pair
    const int slot = (lane >> 3) & 3;    // 0..3
    const int sub  = lane & 7;           // 16B chunk within row
    const int fc   = sub * 8;

    for (int p = gw; p < NPAIRS; p += AGG_WAVES) {
        const int wid = p * 2 + grp;
        const int beg = offsets[wid], end = offsets[wid + 1];

        __half2 h0 = __float2half2_rn(0.f), h1 = h0, h2 = h0, h3 = h0;

        int e = beg + slot;
        for (; e + 12 < end; e += 16) {
            int p0 = csr[e];
            int p1 = csr[e + 4];
            int p2 = csr[e + 8];
            int p3 = csr[e + 12];
            float4 v0 = *(const float4*)(G16 + (size_t)p0 + fc);
            float4 v1 = *(const float4*)(G16 + (size_t)p1 + fc);
            float4 v2 = *(const float4*)(G16 + (size_t)p2 + fc);
            float4 v3 = *(const float4*)(G16 + (size_t)p3 + fc);
            PKACC(v0)
            PKACC(v1)
            PKACC(v2)
            PKACC(v3)
        }
        for (; e + 4 < end; e += 8) {
            int p0 = csr[e];
            int p1 = csr[e + 4];
            float4 v0 = *(const float4*)(G16 + (size_t)p0 + fc);
            float4 v1 = *(const float4*)(G16 + (size_t)p1 + fc);
            PKACC(v0)
            PKACC(v1)
        }
        if (e < end) {
            int p0 = csr[e];
            float4 v0 = *(const float4*)(G16 + (size_t)p0 + fc);
            PKACC(v0)
        }

        float acc[8];
        {
            float2 f;
            f = __half22float2(h0); acc[0] = f.x; acc[1] = f.y;
            f = __half22float2(h1); acc[2] = f.x; acc[3] = f.y;
            f = __half22float2(h2); acc[4] = f.x; acc[5] = f.y;
            f = __half22float2(h3); acc[6] = f.x; acc[7] = f.y;
        }
#pragma unroll
        for (int k = 0; k < 8; ++k) {
            acc[k] += __shfl_xor(acc[k], 8, 64);
            acc[k] += __shfl_xor(acc[k], 16, 64);
        }

        if (slot == 0) {   // lanes 0-7 (node A) and 32-39 (node B)
            float4 vs = *(const float4*)(G16 + (size_t)wid * DIM + fc);
            {
                const __half2* hp = (const __half2*)&vs;
                float2 f0 = __half22float2(hp[0]);
                float2 f1 = __half22float2(hp[1]);
                float2 f2 = __half22float2(hp[2]);
                float2 f3 = __half22float2(hp[3]);
                acc[0] += f0.x; acc[1] += f0.y;
                acc[2] += f1.x; acc[3] += f1.y;
                acc[4] += f2.x; acc[5] += f2.y;
                acc[6] += f3.x; acc[7] += f3.y;
            }

            float di = dinv[wid];
            float4 b0 = *(const float4*)(bias + fc);
            float4 b1 = *(const float4*)(bias + fc + 4);
            float r[8];
            r[0] = di * acc[0] + b0.x;
            r[1] = di * acc[1] + b0.y;
            r[2] = di * acc[2] + b0.z;
            r[3] = di * acc[3] + b0.w;
            r[4] = di * acc[4] + b1.x;
            r[5] = di * acc[5] + b1.y;
            r[6] = di * acc[6] + b1.z;
            r[7] = di * acc[7] + b1.w;
#pragma unroll
            for (int k = 0; k < 8; ++k)
                r[k] = (r[k] >= 0.f) ? r[k] : NEG_SLOPE * r[k];

            if (FINAL) {
                float* out = (float*)outp;
                *(float4*)(out + (size_t)wid * DIM + fc)     = make_float4(r[0], r[1], r[2], r[3]);
                *(float4*)(out + (size_t)wid * DIM + fc + 4) = make_float4(r[4], r[5], r[6], r[7]);
            } else {
                __half* act = (__half*)outp;
                __half2 q0 = __floats2half2_rn(r[0], r[1]);
                __half2 q1 = __floats2half2_rn(r[2], r[3]);
                __half2 q2 = __floats2half2_rn(r[4], r[5]);
                __half2 q3 = __floats2half2_rn(r[6], r[7]);
                uint4 u;
                u.x = *(unsigned int*)&q0;
                u.y = *(unsigned int*)&q1;
                u.z = *(unsigned int*)&q2;
                u.w = *(unsigned int*)&q3;
                *(uint4*)(act + (size_t)wid * DIM + fc) = u;
            }
        }
    }
}
#undef PKACC

extern "C" void kernel_launch(void* const* d_in, const int* in_sizes, int n_in,
                              void* d_out, int out_size, void* d_ws, size_t ws_size,
                              hipStream_t stream) {
    const float* x = (const float*)d_in[0];
    const int* ei = (const int*)d_in[1];
    const int* src = ei;
    const int* dst = ei + N_EDGES;
    const float* W[4] = {(const float*)d_in[2], (const float*)d_in[4],
                         (const float*)d_in[6], (const float*)d_in[8]};
    const float* b[4] = {(const float*)d_in[3], (const float*)d_in[5],
                         (const float*)d_in[7], (const float*)d_in[9]};
    float* out = (float*)d_out;

    char* ws = (char*)d_ws;
    size_t off = 0;
    auto alloc = [&](size_t bytes) -> void* {
        void* p = ws + off;
        off = (off + bytes + 255) & ~(size_t)255;
        return p;
    };
    __half* GA    = (__half*)alloc((size_t)N_NODES * DIM * sizeof(__half));   // 12.8 MB
    __half* GB    = (__half*)alloc((size_t)N_NODES * DIM * sizeof(__half));   // 12.8 MB
    __half* WT16  = (__half*)alloc((size_t)4 * DIM * DIM * sizeof(__half));   // 32 KB
    int*   csr    = (int*)alloc((size_t)N_EDGES * sizeof(int));               // 6.4 MB
    int*   bdata  = (int*)alloc((size_t)PNB * BCAP * sizeof(int));            // 7.2 MB
    int*   gcur   = (int*)alloc((size_t)PNB * 16 * sizeof(int));              // 25 KB
    int*   offsets= (int*)alloc((size_t)(N_NODES + 1) * sizeof(int));
    float* dinv   = (float*)alloc((size_t)N_NODES * sizeof(float));

    // prep_weights blocks 0-3 convert W; blocks 4-7 zero gcur (memset folded in)
    prep_weights<<<8, 256, 0, stream>>>(W[0], W[1], W[2], W[3], WT16, gcur);

    bucket_scatter<<<BLOCKS1, THREADS1, 0, stream>>>(src, dst, gcur, bdata);
    bucket_build<<<PNB, 256, 0, stream>>>(bdata, gcur, offsets, dinv, csr);

    const int MM_GRID = (N_NODES + 63) / 64;          // 1563

    // layer 1 transform
    mm_kernel<float><<<MM_GRID, 256, 0, stream>>>(x, WT16, dinv, GA);
    // fused agg(l1)+mm(l2), agg(l2)+mm(l3), agg(l3)+mm(l4)
    fused_agg_mm<<<FNB, 256, 0, stream>>>(GA, csr, offsets, dinv, b[0], WT16 + 1 * DIM * DIM, GB);
    fused_agg_mm<<<FNB, 256, 0, stream>>>(GB, csr, offsets, dinv, b[1], WT16 + 2 * DIM * DIM, GA);
    fused_agg_mm<<<FNB, 256, 0, stream>>>(GA, csr, offsets, dinv, b[2], WT16 + 3 * DIM * DIM, GB);
    // final aggregate -> fp32 out
    agg_kernel<true><<<AGG_BLOCKS, 256, 0, stream>>>(GB, csr, offsets, dinv, b[3], out);
}

// Round 8
// 271.589 us; speedup vs baseline: 2.0510x; 1.0414x over previous
//
#include <hip/hip_runtime.h>
#include <hip/hip_fp16.h>

#define N_NODES 100000
#define N_EDGES 1600000
#define DIM 64
#define NEG_SLOPE 0.01f

// ---- preprocessing bucket geometry (decoupled from fused-kernel tiles) ----
#define PNODES 256            // nodes per preproc bucket
#define PNB 391               // ceil(100000/256)
#define BCAP 4608             // slab capacity per bucket (avg fill ~4092, sd ~64)
#define BLOCKS1 256           // scatter blocks (1 per CU; halves reservation contention)
#define THREADS1 1024         // 16 waves
#define EPB (N_EDGES / BLOCKS1)   // 6250 exactly
#define EPT 7                 // ceil(EPB / THREADS1) register-staged edges per thread

// ---- fused-kernel tile geometry ----
#define FNODES 64             // nodes per fused block
#define FNB 1563              // ceil(100000/64)

typedef _Float16 half8 __attribute__((ext_vector_type(8)));
typedef float float4v __attribute__((ext_vector_type(4)));

// ---- weight prep: W fp32 [k][f] -> WT16 fp16 transposed [f][k], 4 layers ----
// blocks 4..7 zero gcur (folds the memset dispatch in here)
__global__ void prep_weights(const float* __restrict__ W0, const float* __restrict__ W1,
                             const float* __restrict__ W2, const float* __restrict__ W3,
                             __half* __restrict__ WT16, int* __restrict__ gcur) {
    if (blockIdx.x < 4) {
        const float* Ws[4] = {W0, W1, W2, W3};
        const float* W = Ws[blockIdx.x];
        __half* dst = WT16 + (size_t)blockIdx.x * DIM * DIM;
        for (int e = threadIdx.x; e < DIM * DIM; e += 256) {
            int k = e >> 6, f = e & 63;
            dst[f * DIM + k] = __float2half(W[e]);
        }
    } else {
        for (int i = (blockIdx.x - 4) * 256 + threadIdx.x; i < PNB * 16; i += 4 * 256)
            gcur[i] = 0;
    }
}

// ---- pass 1: single-pass register-staged counting-sort scatter ----
// Edges are read ONCE (src+dst 12.8 MB total instead of 19.2), held in registers
// across the count/scan/reserve phases, then placed into the LDS-staged slab
// image and written out coalesced.
__global__ __launch_bounds__(THREADS1) void bucket_scatter(const int* __restrict__ src,
                                                           const int* __restrict__ dst,
                                                           int* __restrict__ gcur,   // stride 16 (64B pad)
                                                           int* __restrict__ bdata) {
    __shared__ int cnt[PNB];
    __shared__ int lexcl[PNB];
    __shared__ int base[PNB];
    __shared__ int wsum[THREADS1 / 64];
    __shared__ int sorted_e[EPB];              // 25 KB
    __shared__ unsigned short sorted_b[EPB];   // 12.5 KB

    const int tid = threadIdx.x;
    for (int i = tid; i < PNB; i += THREADS1) cnt[i] = 0;
    __syncthreads();

    const int e0 = blockIdx.x * EPB;

    // load + count (edges held in registers)
    int ev[EPT];
    int bv[EPT];
#pragma unroll
    for (int k = 0; k < EPT; ++k) {
        int e = tid + k * THREADS1;
        if (e < EPB) {
            int d = dst[e0 + e];
            int b = d >> 8;
            ev[k] = src[e0 + e] | ((d & 255) << 17);
            bv[k] = b;
            atomicAdd(&cnt[b], 1);
        } else {
            bv[k] = -1;
        }
    }
    __syncthreads();

    // exclusive scan over PNB=391 counters: wave-level shfl scan + wave partials
    int v = (tid < PNB) ? cnt[tid] : 0;
    int incl = v;
#pragma unroll
    for (int s = 1; s < 64; s <<= 1) {
        int up = __shfl_up(incl, s, 64);
        if ((tid & 63) >= s) incl += up;
    }
    if ((tid & 63) == 63) wsum[tid >> 6] = incl;
    __syncthreads();
    int wpre = 0;
    for (int w = 0; w < (tid >> 6); ++w) wpre += wsum[w];
    if (tid < PNB) lexcl[tid] = wpre + incl - v;

    // global slab reservation; reuse cnt as intra-block cursor
    for (int i = tid; i < PNB; i += THREADS1) {
        int c = cnt[i];
        base[i] = c ? atomicAdd(&gcur[i * 16], c) : 0;
        cnt[i] = 0;
    }
    __syncthreads();

    // placement from registers
#pragma unroll
    for (int k = 0; k < EPT; ++k) {
        int b = bv[k];
        if (b >= 0) {
            int p = lexcl[b] + atomicAdd(&cnt[b], 1);
            sorted_e[p] = ev[k];
            sorted_b[p] = (unsigned short)b;
        }
    }
    __syncthreads();

    // coalesced writeout: runs of avg ~16 consecutive slots per bucket
    for (int i = tid; i < EPB; i += THREADS1) {
        int b = sorted_b[i];
        bdata[(size_t)b * BCAP + base[b] + (i - lexcl[b])] = sorted_e[i];
    }
}

// ---- pass 2: per-bucket counting sort -> offsets, dinv, csr (parallel scan) ----
__global__ __launch_bounds__(256) void bucket_build(const int* __restrict__ bdata,
                                                    const int* __restrict__ gcur,
                                                    int* __restrict__ offsets,
                                                    float* __restrict__ dinv,
                                                    int* __restrict__ csr) {
    __shared__ int cnt[PNODES];
    __shared__ int excl[PNODES];
    __shared__ int part[256];
    __shared__ int wsum[4];
    const int tid = threadIdx.x;
    const int b = blockIdx.x;
    const int sz = gcur[b * 16];
    const int* bd = bdata + (size_t)b * BCAP;

    // cbase = sum of bucket sizes for buckets < b (parallel reduce, L2-hot)
    int s = 0;
    for (int i = tid; i < b; i += 256) s += gcur[i * 16];
    part[tid] = s;
    __syncthreads();
    for (int st = 128; st > 0; st >>= 1) {
        if (tid < st) part[tid] += part[tid + st];
        __syncthreads();
    }
    const int cbase = part[0];
    __syncthreads();

    cnt[tid] = 0;
    __syncthreads();
    for (int i = tid; i < sz; i += 256)
        atomicAdd(&cnt[bd[i] >> 17], 1);
    __syncthreads();

    // parallel exclusive scan over 256 counters (tid == local node)
    {
        int v = cnt[tid];
        int incl = v;
#pragma unroll
        for (int sh = 1; sh < 64; sh <<= 1) {
            int up = __shfl_up(incl, sh, 64);
            if ((tid & 63) >= sh) incl += up;
        }
        if ((tid & 63) == 63) wsum[tid >> 6] = incl;
        __syncthreads();
        int wpre = 0;
        for (int w = 0; w < (tid >> 6); ++w) wpre += wsum[w];
        excl[tid] = wpre + incl - v;
    }
    __syncthreads();

    const int nb = b * PNODES;
    {
        int n = nb + tid;
        if (n < N_NODES) {
            offsets[n] = cbase + excl[tid];
            dinv[n] = rsqrtf((float)(cnt[tid] + 1));   // deg incl self-loop
        }
    }
    if (b == PNB - 1 && tid == 0) offsets[N_NODES] = N_EDGES;

    cnt[tid] = 0;   // reuse as cursor
    __syncthreads();
    for (int i = tid; i < sz; i += 256) {
        int v = bd[i];
        int l = v >> 17;
        int pos = cbase + excl[l] + atomicAdd(&cnt[l], 1);
        csr[pos] = (v & 0x1FFFF) << 6;   // element offset src*DIM
    }
}

// ---- staging helpers ----
__device__ __forceinline__ void stage8(__half* dst, const float* __restrict__ X, size_t off) {
    float4 f0 = *(const float4*)(X + off);
    float4 f1 = *(const float4*)(X + off + 4);
    __half2 h0 = __floats2half2_rn(f0.x, f0.y);
    __half2 h1 = __floats2half2_rn(f0.z, f0.w);
    __half2 h2 = __floats2half2_rn(f1.x, f1.y);
    __half2 h3 = __floats2half2_rn(f1.z, f1.w);
    uint4 u;
    u.x = *(unsigned int*)&h0; u.y = *(unsigned int*)&h1;
    u.z = *(unsigned int*)&h2; u.w = *(unsigned int*)&h3;
    *(uint4*)dst = u;
}
__device__ __forceinline__ void stage8(__half* dst, const __half* __restrict__ X, size_t off) {
    *(uint4*)dst = *(const uint4*)(X + off);
}

// ---- MFMA fp16 matmul + dinv: G16[r,f] = (half) dinv[r] * sum_k X[r,k] W[k,f] ----
#define XPAD 72
template <typename TIN>
__global__ __launch_bounds__(256) void mm_kernel(const TIN* __restrict__ X,
                                                 const __half* __restrict__ WT,  // [f][k] fp16
                                                 const float* __restrict__ dinv,
                                                 __half* __restrict__ G16) {
    __shared__ __align__(16) __half xs[64][XPAD];
    __shared__ __align__(16) __half ws[64][XPAD];
    const int t = threadIdx.x;
    const int rbase = blockIdx.x * 64;

    for (int c = t; c < 512; c += 256) {
        int row = c >> 3, koff = (c & 7) * 8;
        int grow = rbase + row;
        if (grow < N_NODES) {
            stage8(&xs[row][koff], X, (size_t)grow * DIM + koff);
        } else {
            *(uint4*)&xs[row][koff] = make_uint4(0, 0, 0, 0);
        }
        stage8(&ws[row][koff], WT, (size_t)row * DIM + koff);
    }
    __syncthreads();

    const int wave = t >> 6;
    const int lane = t & 63;
    const int q = lane >> 4;
    const int c16 = lane & 15;
    const int n0 = wave * 16;

    half8 b0 = *(const half8*)&xs[n0 + c16][q * 8];
    half8 b1 = *(const half8*)&xs[n0 + c16][32 + q * 8];

    const int gnode = rbase + n0 + c16;
    float di = (gnode < N_NODES) ? dinv[gnode] : 0.f;

#pragma unroll
    for (int ft = 0; ft < 4; ++ft) {
        const int f0 = ft * 16;
        half8 a0 = *(const half8*)&ws[f0 + c16][q * 8];
        half8 a1 = *(const half8*)&ws[f0 + c16][32 + q * 8];
        float4v acc = {0.f, 0.f, 0.f, 0.f};
        acc = __builtin_amdgcn_mfma_f32_16x16x32_f16(a0, b0, acc, 0, 0, 0);
        acc = __builtin_amdgcn_mfma_f32_16x16x32_f16(a1, b1, acc, 0, 0, 0);
        if (gnode < N_NODES) {
            __half2 p0 = __floats2half2_rn(di * acc[0], di * acc[1]);
            __half2 p1 = __floats2half2_rn(di * acc[2], di * acc[3]);
            uint2 u;
            u.x = *(unsigned int*)&p0;
            u.y = *(unsigned int*)&p1;
            *(uint2*)(G16 + (size_t)gnode * DIM + f0 + q * 4) = u;
        }
    }
}

// shared 4-deep-MLP gather accumulate: per-slot edge sequence identical to the
// old 2-wide loop (e, e+4, e+8, e+12, ...) so results are bit-identical.
#define PKACC(vraw)                                     \
        {                                               \
            const __half2* hp = (const __half2*)&(vraw);\
            h0 = __hadd2(h0, hp[0]);                    \
            h1 = __hadd2(h1, hp[1]);                    \
            h2 = __hadd2(h2, hp[2]);                    \
            h3 = __hadd2(h3, hp[3]);                    \
        }

// ---------------- fused: agg(layer i) into LDS + mm(layer i+1) ----------------
__global__ __launch_bounds__(256) void fused_agg_mm(const __half* __restrict__ Gin,
                                                    const int* __restrict__ csr,
                                                    const int* __restrict__ offsets,
                                                    const float* __restrict__ dinv,
                                                    const float* __restrict__ bias,
                                                    const __half* __restrict__ WT,  // next layer [f][k]
                                                    __half* __restrict__ Gout) {
    __shared__ __align__(16) __half act[64][XPAD];
    __shared__ __align__(16) __half ws[64][XPAD];
    const int t = threadIdx.x;
    const int blk = blockIdx.x;
    const int nb = blk * FNODES;

    // stage next layer's W tile (read in phase 2, after the barrier)
    for (int c = t; c < 512; c += 256) {
        int row = c >> 3, koff = (c & 7) * 8;
        stage8(&ws[row][koff], WT, (size_t)row * DIM + koff);
    }

    const int wave = t >> 6;
    const int lane = t & 63;
    const int grp  = lane >> 5;          // node of the pair
    const int slot = (lane >> 3) & 3;    // 0..3
    const int sub  = lane & 7;           // 16B chunk within row
    const int fc   = sub * 8;

    // ---- phase 1: aggregate 16 nodes per wave (8 pairs) ----
    for (int i = 0; i < 8; ++i) {
        const int lrow = wave * 16 + i * 2 + grp;   // 0..63 local row
        const int wid = nb + lrow;
        const bool valid = (wid < N_NODES);
        const int beg = valid ? offsets[wid] : 0;
        const int end = valid ? offsets[wid + 1] : 0;

        __half2 h0 = __float2half2_rn(0.f), h1 = h0, h2 = h0, h3 = h0;

        int e = beg + slot;
        for (; e + 12 < end; e += 16) {
            int p0 = csr[e];
            int p1 = csr[e + 4];
            int p2 = csr[e + 8];
            int p3 = csr[e + 12];
            float4 v0 = *(const float4*)(Gin + (size_t)p0 + fc);
            float4 v1 = *(const float4*)(Gin + (size_t)p1 + fc);
            float4 v2 = *(const float4*)(Gin + (size_t)p2 + fc);
            float4 v3 = *(const float4*)(Gin + (size_t)p3 + fc);
            PKACC(v0)
            PKACC(v1)
            PKACC(v2)
            PKACC(v3)
        }
        for (; e + 4 < end; e += 8) {
            int p0 = csr[e];
            int p1 = csr[e + 4];
            float4 v0 = *(const float4*)(Gin + (size_t)p0 + fc);
            float4 v1 = *(const float4*)(Gin + (size_t)p1 + fc);
            PKACC(v0)
            PKACC(v1)
        }
        if (e < end) {
            int p0 = csr[e];
            float4 v0 = *(const float4*)(Gin + (size_t)p0 + fc);
            PKACC(v0)
        }

        float acc[8];
        {
            float2 f;
            f = __half22float2(h0); acc[0] = f.x; acc[1] = f.y;
            f = __half22float2(h1); acc[2] = f.x; acc[3] = f.y;
            f = __half22float2(h2); acc[4] = f.x; acc[5] = f.y;
            f = __half22float2(h3); acc[6] = f.x; acc[7] = f.y;
        }
#pragma unroll
        for (int k = 0; k < 8; ++k) {
            acc[k] += __shfl_xor(acc[k], 8, 64);
            acc[k] += __shfl_xor(acc[k], 16, 64);
        }

        if (slot == 0) {   // lanes 0-7 (node A) and 32-39 (node B): full 64-elem row
            uint4 u = make_uint4(0, 0, 0, 0);
            if (valid) {
                // self-loop row, exactly once, post-reduction
                float4 vs = *(const float4*)(Gin + (size_t)wid * DIM + fc);
                {
                    const __half2* hp = (const __half2*)&vs;
                    float2 f0 = __half22float2(hp[0]);
                    float2 f1 = __half22float2(hp[1]);
                    float2 f2 = __half22float2(hp[2]);
                    float2 f3 = __half22float2(hp[3]);
                    acc[0] += f0.x; acc[1] += f0.y;
                    acc[2] += f1.x; acc[3] += f1.y;
                    acc[4] += f2.x; acc[5] += f2.y;
                    acc[6] += f3.x; acc[7] += f3.y;
                }
                float di = dinv[wid];
                float4 bb0 = *(const float4*)(bias + fc);
                float4 bb1 = *(const float4*)(bias + fc + 4);
                float r[8];
                r[0] = di * acc[0] + bb0.x;
                r[1] = di * acc[1] + bb0.y;
                r[2] = di * acc[2] + bb0.z;
                r[3] = di * acc[3] + bb0.w;
                r[4] = di * acc[4] + bb1.x;
                r[5] = di * acc[5] + bb1.y;
                r[6] = di * acc[6] + bb1.z;
                r[7] = di * acc[7] + bb1.w;
#pragma unroll
                for (int k = 0; k < 8; ++k)
                    r[k] = (r[k] >= 0.f) ? r[k] : NEG_SLOPE * r[k];
                __half2 q0 = __floats2half2_rn(r[0], r[1]);
                __half2 q1 = __floats2half2_rn(r[2], r[3]);
                __half2 q2 = __floats2half2_rn(r[4], r[5]);
                __half2 q3 = __floats2half2_rn(r[6], r[7]);
                u.x = *(unsigned int*)&q0;
                u.y = *(unsigned int*)&q1;
                u.z = *(unsigned int*)&q2;
                u.w = *(unsigned int*)&q3;
            }
            *(uint4*)(&act[lrow][fc]) = u;
        }
    }
    __syncthreads();

    // ---- phase 2: Gout[n] = dinv[n] * (act[n] @ W) ----
    const int q = lane >> 4;
    const int c16 = lane & 15;
    const int n0 = wave * 16;

    half8 xb0 = *(const half8*)&act[n0 + c16][q * 8];
    half8 xb1 = *(const half8*)&act[n0 + c16][32 + q * 8];

    const int gnode = nb + n0 + c16;
    float dio = (gnode < N_NODES) ? dinv[gnode] : 0.f;

#pragma unroll
    for (int ft = 0; ft < 4; ++ft) {
        const int f0 = ft * 16;
        half8 a0 = *(const half8*)&ws[f0 + c16][q * 8];
        half8 a1 = *(const half8*)&ws[f0 + c16][32 + q * 8];
        float4v accv = {0.f, 0.f, 0.f, 0.f};
        accv = __builtin_amdgcn_mfma_f32_16x16x32_f16(a0, xb0, accv, 0, 0, 0);
        accv = __builtin_amdgcn_mfma_f32_16x16x32_f16(a1, xb1, accv, 0, 0, 0);
        if (gnode < N_NODES) {
            __half2 p0 = __floats2half2_rn(dio * accv[0], dio * accv[1]);
            __half2 p1 = __floats2half2_rn(dio * accv[2], dio * accv[3]);
            uint2 u;
            u.x = *(unsigned int*)&p0;
            u.y = *(unsigned int*)&p1;
            *(uint2*)(Gout + (size_t)gnode * DIM + f0 + q * 4) = u;
        }
    }
}

// ---------------- final aggregate: persistent waves, 2 nodes per wave ----------------
#define AGG_BLOCKS 2048
#define AGG_WAVES (AGG_BLOCKS * 4)
#define NPAIRS (N_NODES / 2)
template <bool FINAL>
__global__ __launch_bounds__(256) void agg_kernel(const __half* __restrict__ G16,
                                                  const int* __restrict__ csr,
                                                  const int* __restrict__ offsets,
                                                  const float* __restrict__ dinv,
                                                  const float* __restrict__ bias,
                                                  void* __restrict__ outp) {
    const int gw = (blockIdx.x * 256 + threadIdx.x) >> 6;   // global wave id
    const int lane = threadIdx.x & 63;
    const int grp  = lane >> 5;          // node of the pair
    const int slot = (lane >> 3) & 3;    // 0..3
    const int sub  = lane & 7;           // 16B chunk within row
    const int fc   = sub * 8;

    for (int p = gw; p < NPAIRS; p += AGG_WAVES) {
        const int wid = p * 2 + grp;
        const int beg = offsets[wid], end = offsets[wid + 1];

        __half2 h0 = __float2half2_rn(0.f), h1 = h0, h2 = h0, h3 = h0;

        int e = beg + slot;
        for (; e + 12 < end; e += 16) {
            int p0 = csr[e];
            int p1 = csr[e + 4];
            int p2 = csr[e + 8];
            int p3 = csr[e + 12];
            float4 v0 = *(const float4*)(G16 + (size_t)p0 + fc);
            float4 v1 = *(const float4*)(G16 + (size_t)p1 + fc);
            float4 v2 = *(const float4*)(G16 + (size_t)p2 + fc);
            float4 v3 = *(const float4*)(G16 + (size_t)p3 + fc);
            PKACC(v0)
            PKACC(v1)
            PKACC(v2)
            PKACC(v3)
        }
        for (; e + 4 < end; e += 8) {
            int p0 = csr[e];
            int p1 = csr[e + 4];
            float4 v0 = *(const float4*)(G16 + (size_t)p0 + fc);
            float4 v1 = *(const float4*)(G16 + (size_t)p1 + fc);
            PKACC(v0)
            PKACC(v1)
        }
        if (e < end) {
            int p0 = csr[e];
            float4 v0 = *(const float4*)(G16 + (size_t)p0 + fc);
            PKACC(v0)
        }

        float acc[8];
        {
            float2 f;
            f = __half22float2(h0); acc[0] = f.x; acc[1] = f.y;
            f = __half22float2(h1); acc[2] = f.x; acc[3] = f.y;
            f = __half22float2(h2); acc[4] = f.x; acc[5] = f.y;
            f = __half22float2(h3); acc[6] = f.x; acc[7] = f.y;
        }
#pragma unroll
        for (int k = 0; k < 8; ++k) {
            acc[k] += __shfl_xor(acc[k], 8, 64);
            acc[k] += __shfl_xor(acc[k], 16, 64);
        }

        if (slot == 0) {   // lanes 0-7 (node A) and 32-39 (node B)
            float4 vs = *(const float4*)(G16 + (size_t)wid * DIM + fc);
            {
                const __half2* hp = (const __half2*)&vs;
                float2 f0 = __half22float2(hp[0]);
                float2 f1 = __half22float2(hp[1]);
                float2 f2 = __half22float2(hp[2]);
                float2 f3 = __half22float2(hp[3]);
                acc[0] += f0.x; acc[1] += f0.y;
                acc[2] += f1.x; acc[3] += f1.y;
                acc[4] += f2.x; acc[5] += f2.y;
                acc[6] += f3.x; acc[7] += f3.y;
            }

            float di = dinv[wid];
            float4 b0 = *(const float4*)(bias + fc);
            float4 b1 = *(const float4*)(bias + fc + 4);
            float r[8];
            r[0] = di * acc[0] + b0.x;
            r[1] = di * acc[1] + b0.y;
            r[2] = di * acc[2] + b0.z;
            r[3] = di * acc[3] + b0.w;
            r[4] = di * acc[4] + b1.x;
            r[5] = di * acc[5] + b1.y;
            r[6] = di * acc[6] + b1.z;
            r[7] = di * acc[7] + b1.w;
#pragma unroll
            for (int k = 0; k < 8; ++k)
                r[k] = (r[k] >= 0.f) ? r[k] : NEG_SLOPE * r[k];

            if (FINAL) {
                float* out = (float*)outp;
                *(float4*)(out + (size_t)wid * DIM + fc)     = make_float4(r[0], r[1], r[2], r[3]);
                *(float4*)(out + (size_t)wid * DIM + fc + 4) = make_float4(r[4], r[5], r[6], r[7]);
            } else {
                __half* act = (__half*)outp;
                __half2 q0 = __floats2half2_rn(r[0], r[1]);
                __half2 q1 = __floats2half2_rn(r[2], r[3]);
                __half2 q2 = __floats2half2_rn(r[4], r[5]);
                __half2 q3 = __floats2half2_rn(r[6], r[7]);
                uint4 u;
                u.x = *(unsigned int*)&q0;
                u.y = *(unsigned int*)&q1;
                u.z = *(unsigned int*)&q2;
                u.w = *(unsigned int*)&q3;
                *(uint4*)(act + (size_t)wid * DIM + fc) = u;
            }
        }
    }
}
#undef PKACC

extern "C" void kernel_launch(void* const* d_in, const int* in_sizes, int n_in,
                              void* d_out, int out_size, void* d_ws, size_t ws_size,
                              hipStream_t stream) {
    const float* x = (const float*)d_in[0];
    const int* ei = (const int*)d_in[1];
    const int* src = ei;
    const int* dst = ei + N_EDGES;
    const float* W[4] = {(const float*)d_in[2], (const float*)d_in[4],
                         (const float*)d_in[6], (const float*)d_in[8]};
    const float* b[4] = {(const float*)d_in[3], (const float*)d_in[5],
                         (const float*)d_in[7], (const float*)d_in[9]};
    float* out = (float*)d_out;

    char* ws = (char*)d_ws;
    size_t off = 0;
    auto alloc = [&](size_t bytes) -> void* {
        void* p = ws + off;
        off = (off + bytes + 255) & ~(size_t)255;
        return p;
    };
    __half* GA    = (__half*)alloc((size_t)N_NODES * DIM * sizeof(__half));   // 12.8 MB
    __half* GB    = (__half*)alloc((size_t)N_NODES * DIM * sizeof(__half));   // 12.8 MB
    __half* WT16  = (__half*)alloc((size_t)4 * DIM * DIM * sizeof(__half));   // 32 KB
    int*   csr    = (int*)alloc((size_t)N_EDGES * sizeof(int));               // 6.4 MB
    int*   bdata  = (int*)alloc((size_t)PNB * BCAP * sizeof(int));            // 7.2 MB
    int*   gcur   = (int*)alloc((size_t)PNB * 16 * sizeof(int));              // 25 KB
    int*   offsets= (int*)alloc((size_t)(N_NODES + 1) * sizeof(int));
    float* dinv   = (float*)alloc((size_t)N_NODES * sizeof(float));

    // prep_weights blocks 0-3 convert W; blocks 4-7 zero gcur (memset folded in)
    prep_weights<<<8, 256, 0, stream>>>(W[0], W[1], W[2], W[3], WT16, gcur);

    bucket_scatter<<<BLOCKS1, THREADS1, 0, stream>>>(src, dst, gcur, bdata);
    bucket_build<<<PNB, 256, 0, stream>>>(bdata, gcur, offsets, dinv, csr);

    const int MM_GRID = (N_NODES + 63) / 64;          // 1563

    // layer 1 transform
    mm_kernel<float><<<MM_GRID, 256, 0, stream>>>(x, WT16, dinv, GA);
    // fused agg(l1)+mm(l2), agg(l2)+mm(l3), agg(l3)+mm(l4)
    fused_agg_mm<<<FNB, 256, 0, stream>>>(GA, csr, offsets, dinv, b[0], WT16 + 1 * DIM * DIM, GB);
    fused_agg_mm<<<FNB, 256, 0, stream>>>(GB, csr, offsets, dinv, b[1], WT16 + 2 * DIM * DIM, GA);
    fused_agg_mm<<<FNB, 256, 0, stream>>>(GA, csr, offsets, dinv, b[2], WT16 + 3 * DIM * DIM, GB);
    // final aggregate -> fp32 out
    agg_kernel<true><<<AGG_BLOCKS, 256, 0, stream>>>(GB, csr, offsets, dinv, b[3], out);
}